// Round 4
// baseline (805.653 us; speedup 1.0000x reference)
//
#include <hip/hip_runtime.h>
#include <math.h>

#pragma clang fp contract(off)

#define NPTS 4096
#define PTS  32768
#define ROWS 163840   // PTS * 5
#define QLEN 1024     // NPTS / 4
#define TOPQ 6

// LAPACK single-precision machine constants (gfortran/IEEE):
#define EPS_L   5.9604644775390625e-8f    // 2^-24  SLAMCH('E')
#define EPS2_L  3.5527136788005009e-15f   // 2^-48
#define SAFMIN_L 1.1754943508222875e-38f  // 2^-126

// Round-to-nearest, non-contractible f32 ops (file pragma disables fusion).
__device__ __forceinline__ float frn_mul(float a, float b) { float r = a * b; return r; }
__device__ __forceinline__ float frn_add(float a, float b) { float r = a + b; return r; }
__device__ __forceinline__ float frn_sub(float a, float b) { float r = a - b; return r; }
__device__ __forceinline__ float frn_div(float a, float b) { float r = a / b; return r; }

// sq[n] = fl(fl(x0^2) + fl(x1^2))  (strict elementwise mul + 2-term reduce)
__device__ __forceinline__ float ref_sq(float x0, float x1) {
  return frn_add(frn_mul(x0, x0), frn_mul(x1, x1));
}
// dist_sq[n,m] = fl( fl(sq_n + sq_m) - 2*dot ), where dot replicates an
// ascending-k FMA GEMM microkernel (k=2, acc starts at 0):
//   dot = fma(ny*my, fl(nx*mx))   [first product rounded, second exact in fma]
__device__ __forceinline__ float ref_key(float nx, float ny, float sqn,
                                         float mx, float my, float sqm) {
  float dot = fmaf(ny, my, frn_mul(nx, mx));
  float s = frn_add(sqn, sqm);
  return frn_sub(s, frn_add(dot, dot));
}

// ---------------------------------------------------------------------------
// Weight transpose prep: wt[j*K + i] = w[i*N + j]
// ---------------------------------------------------------------------------
__global__ __launch_bounds__(256) void prep_w(
    const float* __restrict__ lw1, const float* __restrict__ lw2, const float* __restrict__ lw3,
    const float* __restrict__ cw1, const float* __restrict__ cw2,
    const float* __restrict__ tw1, const float* __restrict__ tw2,
    float* __restrict__ wt) {
  const int Ks[7]   = {2, 64, 128, 66, 128, 64, 128};
  const int Ns[7]   = {64, 128, 64, 128, 128, 128, 128};
  const int offs[7] = {0, 128, 8320, 16512, 24960, 41344, 49536};
  const float* srcs[7] = {lw1, lw2, lw3, cw1, cw2, tw1, tw2};
  int b = blockIdx.x;
  const float* src = srcs[b];
  float* dst = wt + offs[b];
  int K = Ks[b], N = Ns[b];
  for (int e = threadIdx.x; e < K * N; e += 256) {
    int j = e / K, i = e - j * K;
    dst[e] = src[i * N + j];
  }
}

// ---------------------------------------------------------------------------
// kNN scan: 512 blocks = 128 point-groups x 4 candidate-quarters.
// Ranks by the REFERENCE's noisy f32 expanded-form key (bitwise replica),
// ties broken by lower index (stable-sort / lax.top_k rule). Top-6/quarter.
// ---------------------------------------------------------------------------
__global__ __launch_bounds__(256) void knn_scan(const float* __restrict__ x,
                                                int* __restrict__ ipart) {
  __shared__ float cx_[QLEN], cy_[QLEN], cs_[QLEN];
  int bx = blockIdx.x;
  int q = bx & 3;
  int pg = bx >> 2;                 // 0..127, 256 points each
  int batch = pg >> 4;              // 16 groups per batch
  const float* xb = x + (size_t)batch * NPTS * 2;
  int c0 = q * QLEN;
  for (int i = threadIdx.x; i < QLEN; i += 256) {
    float2 c = ((const float2*)xb)[c0 + i];
    cx_[i] = c.x; cy_[i] = c.y; cs_[i] = ref_sq(c.x, c.y);
  }
  __syncthreads();
  int p = pg * 256 + threadIdx.x;   // global point id
  float2 me = ((const float2*)x)[p];
  float sqn = ref_sq(me.x, me.y);
  float d[TOPQ]; int id[TOPQ];
#pragma unroll
  for (int s = 0; s < TOPQ; s++) { d[s] = 3.0e38f; id[s] = 0x7fffffff; }
  for (int m = 0; m < QLEN; m++) {
    float key = ref_key(me.x, me.y, sqn, cx_[m], cy_[m], cs_[m]);
    int vi = c0 + m;
    if (key < d[TOPQ - 1] || (key == d[TOPQ - 1] && vi < id[TOPQ - 1])) {
      float v = key;
#pragma unroll
      for (int s = 0; s < TOPQ; s++) {
        bool lt = (v < d[s]) || (v == d[s] && vi < id[s]);
        float tv = d[s]; int ti = id[s];
        if (lt) { d[s] = v; id[s] = vi; v = tv; vi = ti; }
      }
    }
  }
  size_t base = ((size_t)q * PTS + p) * TOPQ;
#pragma unroll
  for (int s = 0; s < TOPQ; s++) ipart[base + s] = id[s];
}

// ---------------------------------------------------------------------------
// Merge 4x6 candidates by (ref f32 key, idx) lex -> exact reference top-5.
// Then geometry with bitwise np-order f32 sums, and a faithful replica of
// ssyevd->ssteqr on the 2x2 (negligible-E tests, SLAEV2, ascending sort).
// ---------------------------------------------------------------------------
__global__ __launch_bounds__(256) void merge_geom(const float* __restrict__ x,
    const int* __restrict__ ipart, float* __restrict__ lcct,
    float* __restrict__ angle_out, float* __restrict__ axes_out) {
  int p = blockIdx.x * 256 + threadIdx.x;
  int batch = p >> 12;
  const float2* xb = (const float2*)(x + (size_t)batch * NPTS * 2);
  float2 me = ((const float2*)x)[p];
  float sqn = ref_sq(me.x, me.y);
  float dk[5]; int id[5];
#pragma unroll
  for (int s = 0; s < 5; s++) { dk[s] = 3.0e38f; id[s] = 0x7fffffff; }
  for (int q = 0; q < 4; q++) {
    size_t base = ((size_t)q * PTS + p) * TOPQ;
#pragma unroll
    for (int s6 = 0; s6 < TOPQ; s6++) {
      int ci = ipart[base + s6];
      float2 c = xb[ci];
      float key = ref_key(me.x, me.y, sqn, c.x, c.y, ref_sq(c.x, c.y));
      float v = key; int vi = ci;
#pragma unroll
      for (int s = 0; s < 5; s++) {
        bool lt = (v < dk[s]) || (v == dk[s] && vi < id[s]);
        float tv = dk[s]; int ti = id[s];
        if (lt) { dk[s] = v; id[s] = vi; v = tv; vi = ti; }
      }
    }
  }
  // rel, mean (np sequential order), centered
  float rx[5], ry[5];
  float sx = 0.f, sy = 0.f;
#pragma unroll
  for (int k = 0; k < 5; k++) {
    float2 nb = xb[id[k]];
    rx[k] = frn_sub(nb.x, me.x); ry[k] = frn_sub(nb.y, me.y);
    sx = frn_add(sx, rx[k]); sy = frn_add(sy, ry[k]);
  }
  float mx = frn_div(sx, 5.0f), my = frn_div(sy, 5.0f);
  float c00 = 0.f, c01 = 0.f, c11 = 0.f;
#pragma unroll
  for (int k = 0; k < 5; k++) {
    rx[k] = frn_sub(rx[k], mx); ry[k] = frn_sub(ry[k], my);
    c00 = frn_add(c00, frn_mul(rx[k], rx[k]));
    c01 = frn_add(c01, frn_mul(rx[k], ry[k]));
    c11 = frn_add(c11, frn_mul(ry[k], ry[k]));
  }
  c00 = frn_div(c00, 4.0f); c01 = frn_div(c01, 4.0f); c11 = frn_div(c11, 4.0f);
  float A = frn_add(c00, 1e-6f), Bv = c01, C = frn_add(c11, 1e-6f);

  // ---- ssteqr 2x2 replica ----
  float absA = fabsf(A), absC = fabsf(C), absB = fabsf(Bv);
  // outer split test: |E| <= (sqrt|D1|*sqrt|D2|)*eps
  float thr = frn_mul(frn_mul(sqrtf(absA), sqrtf(absC)), EPS_L);
  bool diag = (absB == 0.f) || (absB <= thr);
  if (!diag) {
    bool qr = (absC < absA);              // ABS(D(LEND)) < ABS(D(L))
    float b2 = frn_mul(absB, absB);       // ABS(E)**2
    float t = qr ? frn_add(frn_mul(frn_mul(EPS2_L, absC), absA), SAFMIN_L)
                 : frn_add(frn_mul(frn_mul(EPS2_L, absA), absC), SAFMIN_L);
    if (b2 <= t) diag = true;
  }
  // v[:,0]=(v00,v10) (smaller eig e1), v[:,1]=(v01,v11) (larger eig e2)
  float e1, e2, v00, v10, v01, v11;
  if (diag) {
    if (C < A) { e1 = C; e2 = A; v00 = 0.f; v10 = 1.f; v01 = 1.f; v11 = 0.f; }
    else       { e1 = A; e2 = C; v00 = 1.f; v10 = 0.f; v01 = 0.f; v11 = 1.f; }
  } else {
    // ---- SLAEV2 replica ----
    float sm = frn_add(A, C), df = frn_sub(A, C);
    float adf = fabsf(df), tb = frn_add(Bv, Bv), ab = fabsf(tb);
    float rt;
    if (adf > ab) {
      float r = frn_div(ab, adf);
      rt = frn_mul(adf, sqrtf(frn_add(1.0f, frn_mul(r, r))));
    } else if (adf < ab) {
      float r = frn_div(adf, ab);
      rt = frn_mul(ab, sqrtf(frn_add(1.0f, frn_mul(r, r))));
    } else {
      rt = frn_mul(ab, sqrtf(2.0f));
    }
    float acmx, acmn;
    if (absA > absC) { acmx = A; acmn = C; } else { acmx = C; acmn = A; }
    float rt1, rt2; int sgn1;
    if (sm < 0.f) {
      rt1 = frn_mul(0.5f, frn_sub(sm, rt)); sgn1 = -1;
      rt2 = frn_sub(frn_mul(frn_div(acmx, rt1), acmn), frn_mul(frn_div(Bv, rt1), Bv));
    } else if (sm > 0.f) {
      rt1 = frn_mul(0.5f, frn_add(sm, rt)); sgn1 = 1;
      rt2 = frn_sub(frn_mul(frn_div(acmx, rt1), acmn), frn_mul(frn_div(Bv, rt1), Bv));
    } else {
      rt1 = frn_mul(0.5f, rt); rt2 = frn_mul(-0.5f, rt); sgn1 = 1;
    }
    float cs, cs1, sn1; int sgn2;
    if (df >= 0.f) { cs = frn_add(df, rt); sgn2 = 1; }
    else           { cs = frn_sub(df, rt); sgn2 = -1; }
    float acs = fabsf(cs);
    if (acs > ab) {
      float ct = frn_div(-tb, cs);
      sn1 = frn_div(1.0f, sqrtf(frn_add(1.0f, frn_mul(ct, ct))));
      cs1 = frn_mul(ct, sn1);
    } else {
      if (ab == 0.f) { cs1 = 1.0f; sn1 = 0.0f; }
      else {
        float tn = frn_div(-cs, tb);
        cs1 = frn_div(1.0f, sqrtf(frn_add(1.0f, frn_mul(tn, tn))));
        sn1 = frn_mul(tn, cs1);
      }
    }
    if (sgn1 == sgn2) { float t = cs1; cs1 = -sn1; sn1 = t; }
    // steqr: D=(RT1,RT2), Z=[(cs1,sn1)|(-sn1,cs1)]; ascending sort swaps
    // columns iff RT2 < RT1 (strict).
    if (rt2 < rt1) { e1 = rt2; e2 = rt1; v00 = -sn1; v10 = cs1; v01 = cs1;  v11 = sn1; }
    else           { e1 = rt1; e2 = rt2; v00 = cs1;  v10 = sn1; v01 = -sn1; v11 = cs1; }
  }

  angle_out[p] = atan2f(v11, v01);
  float aM = sqrtf(fmaxf(e2, 1e-6f));
  float am = sqrtf(fmaxf(e1, 1e-6f));
  float den = frn_add(fmaxf(aM, am), 1e-6f);
  axes_out[2 * p]     = fmaxf(frn_div(aM, den), 0.2f);
  axes_out[2 * p + 1] = fmaxf(frn_div(am, den), 0.2f);
  size_t row = (size_t)p * 5;
#pragma unroll
  for (int k = 0; k < 5; k++) {
    lcct[row + k]        = frn_add(frn_mul(rx[k], v00), frn_mul(ry[k], v10));
    lcct[ROWS + row + k] = frn_add(frn_mul(rx[k], v01), frn_mul(ry[k], v11));
  }
}

// ---------------------------------------------------------------------------
// Dense layer: thread-per-row, feature-major I/O (lane-coalesced),
// wave-uniform weight reads (scalar loads), 4 accumulators for ILP. ReLU.
// ---------------------------------------------------------------------------
template <int K, int NO>
__global__ __launch_bounds__(256) void dense_k(const float* __restrict__ in_t, int in_stride, int in_off,
                                               const float* __restrict__ wt, const float* __restrict__ bias,
                                               float* __restrict__ out_t, int out_stride,
                                               int M) {
  int r = blockIdx.x * 256 + threadIdx.x;
  if (r >= M) return;
  int per = NO / gridDim.y;
  int jlo = blockIdx.y * per, jhi = jlo + per;
  float in[K];
#pragma unroll
  for (int i = 0; i < K; i++) in[i] = in_t[(size_t)i * in_stride + in_off + r];
  for (int j = jlo; j < jhi; j += 4) {
    float acc0 = bias[j], acc1 = bias[j + 1], acc2 = bias[j + 2], acc3 = bias[j + 3];
    const float* w0 = wt + (size_t)j * K;
#pragma unroll
    for (int i = 0; i < K; i++) {
      float xi = in[i];
      acc0 = fmaf(xi, w0[i], acc0);
      acc1 = fmaf(xi, w0[K + i], acc1);
      acc2 = fmaf(xi, w0[2 * K + i], acc2);
      acc3 = fmaf(xi, w0[3 * K + i], acc3);
    }
    out_t[(size_t)j * out_stride + r]       = fmaxf(acc0, 0.f);
    out_t[(size_t)(j + 1) * out_stride + r] = fmaxf(acc1, 0.f);
    out_t[(size_t)(j + 2) * out_stride + r] = fmaxf(acc2, 0.f);
    out_t[(size_t)(j + 3) * out_stride + r] = fmaxf(acc3, 0.f);
  }
}

// ---------------------------------------------------------------------------
// Max over K=5 rows -> lftx rows 2..65 ; rows 0..1 = x passthrough.
// ---------------------------------------------------------------------------
__global__ __launch_bounds__(256) void maxpack(const float* __restrict__ h3, int rows_c, int p_shift, int pbase,
                                               const float* __restrict__ x, float* __restrict__ lftx) {
  int idx = blockIdx.x * 256 + threadIdx.x;
  int pts_c = 1 << p_shift;
  int f = idx >> p_shift;
  int pl = idx & (pts_c - 1);
  int p = pbase + pl;
  if (f < 64) {
    const float* hr = h3 + (size_t)f * rows_c + (size_t)pl * 5;
    float m = fmaxf(fmaxf(fmaxf(hr[0], hr[1]), fmaxf(hr[2], hr[3])), hr[4]);
    lftx[(size_t)(f + 2) * PTS + p] = m;
  } else if (f < 66) {
    int i = f - 64;
    lftx[(size_t)i * PTS + p] = x[(size_t)p * 2 + i];
  }
}

// ---------------------------------------------------------------------------
// Transpose [256][32768] feature-major head outputs into d_out row-major.
// ---------------------------------------------------------------------------
__global__ __launch_bounds__(256) void transpose_out(const float* __restrict__ o_t, float* __restrict__ out) {
  __shared__ float tile[64][65];
  int p0 = blockIdx.x * 64;
  int j0 = blockIdx.y * 64;
  int tc = threadIdx.x & 63, tr = threadIdx.x >> 6;
#pragma unroll
  for (int rr = 0; rr < 16; rr++) {
    int j = tr + rr * 4;
    tile[j][tc] = o_t[(size_t)(j0 + j) * PTS + p0 + tc];
  }
  __syncthreads();
#pragma unroll
  for (int rr = 0; rr < 16; rr++) {
    int pl = tr + rr * 4;
    int p = p0 + pl;
    int j = j0 + tc;
    float v = tile[tc][pl];
    size_t o = (j < 128) ? ((size_t)p * 128 + j)
                         : ((size_t)4194304 + (size_t)p * 128 + (j - 128));
    out[o] = v;
  }
}

// ---------------------------------------------------------------------------
extern "C" void kernel_launch(void* const* d_in, const int* in_sizes, int n_in,
                              void* d_out, int out_size, void* d_ws, size_t ws_size,
                              hipStream_t stream) {
  const float* x   = (const float*)d_in[0];
  const float* lb1 = (const float*)d_in[2];
  const float* lb2 = (const float*)d_in[4];
  const float* lb3 = (const float*)d_in[6];
  const float* cb1 = (const float*)d_in[8];
  const float* cb2 = (const float*)d_in[10];
  const float* tb1 = (const float*)d_in[12];
  const float* tb2 = (const float*)d_in[14];

  float* out = (float*)d_out;
  float* angle_out = out + 8388608;   // after cls(4194304)+topo(4194304)
  float* axes_out  = out + 8421376;

  float* W = (float*)d_ws;
  // Segment A (phase-overlapped): knn ipart (786432 ints) lives at W+0 and is
  // dead before the heads reuse the region.
  float* outct = W + 0;              // 128*PTS
  float* outtt = W + 4194304;        // 128*PTS (contiguous with outct)
  float* a1    = W + 8388608;        // 128*PTS
  const size_t segA = 12582912;
  float* lftx = W + segA;                      // 66*PTS = 2162688
  float* lcct = W + segA + 2162688;            // 2*ROWS = 327680
  float* wt   = W + segA + 2162688 + 327680;   // 65920
  float* hbuf = wt + 65920;
  size_t fixed_f = (size_t)(hbuf - W);

  int chunks = 16;
  const int copts[5] = {1, 2, 4, 8, 16};
  for (int ci = 0; ci < 5; ci++) {
    size_t need = (fixed_f + (size_t)(ROWS / copts[ci]) * 256) * sizeof(float);
    if (need <= ws_size) { chunks = copts[ci]; break; }
  }
  int rows_c = ROWS / chunks;
  int pts_c  = PTS / chunks;
  int p_shift = 31 - __builtin_clz((unsigned)pts_c);

  float* h1 = hbuf;
  float* h2 = hbuf + (size_t)rows_c * 64;
  float* h3 = hbuf + (size_t)rows_c * 192;

  prep_w<<<7, 256, 0, stream>>>((const float*)d_in[1], (const float*)d_in[3], (const float*)d_in[5],
                                (const float*)d_in[7], (const float*)d_in[9],
                                (const float*)d_in[11], (const float*)d_in[13], wt);
  knn_scan<<<512, 256, 0, stream>>>(x, (int*)W);
  merge_geom<<<128, 256, 0, stream>>>(x, (const int*)W, lcct, angle_out, axes_out);

  for (int c = 0; c < chunks; c++) {
    int row0 = c * rows_c;
    dense_k<2, 64><<<dim3(rows_c / 256, 1), 256, 0, stream>>>(lcct, ROWS, row0, wt + 0, lb1, h1, rows_c, rows_c);
    dense_k<64, 128><<<dim3(rows_c / 256, 1), 256, 0, stream>>>(h1, rows_c, 0, wt + 128, lb2, h2, rows_c, rows_c);
    dense_k<128, 64><<<dim3(rows_c / 256, 1), 256, 0, stream>>>(h2, rows_c, 0, wt + 8320, lb3, h3, rows_c, rows_c);
    maxpack<<<(66 * pts_c) / 256, 256, 0, stream>>>(h3, rows_c, p_shift, c * pts_c, x, lftx);
  }

  dense_k<66, 128><<<dim3(PTS / 256, 4), 256, 0, stream>>>(lftx, PTS, 0, wt + 16512, cb1, a1, PTS, PTS);
  dense_k<128, 128><<<dim3(PTS / 256, 4), 256, 0, stream>>>(a1, PTS, 0, wt + 24960, cb2, outct, PTS, PTS);
  dense_k<64, 128><<<dim3(PTS / 256, 4), 256, 0, stream>>>(lftx + 2 * PTS, PTS, 0, wt + 41344, tb1, a1, PTS, PTS);
  dense_k<128, 128><<<dim3(PTS / 256, 4), 256, 0, stream>>>(a1, PTS, 0, wt + 49536, tb2, outtt, PTS, PTS);

  transpose_out<<<dim3(512, 4), 256, 0, stream>>>(outct, out);
}

// Round 5
// 542.750 us; speedup vs baseline: 1.4844x; 1.4844x over previous
//
#include <hip/hip_runtime.h>
#include <math.h>

#pragma clang fp contract(off)

#define NPTS 4096
#define PTS  32768
#define ROWS 163840   // PTS * 5
#define QN   8        // candidate slices per batch
#define QLEN 512      // NPTS / QN
#define SLOTS 8       // packed top-k slots per slice (and global survivors)

// LAPACK single-precision machine constants (gfortran/IEEE):
#define EPS_L   5.9604644775390625e-8f    // 2^-24  SLAMCH('E')
#define EPS2_L  3.5527136788005009e-15f   // 2^-48
#define SAFMIN_L 1.1754943508222875e-38f  // 2^-126

// Round-to-nearest, non-contractible f32 ops (file pragma disables fusion).
__device__ __forceinline__ float frn_mul(float a, float b) { float r = a * b; return r; }
__device__ __forceinline__ float frn_add(float a, float b) { float r = a + b; return r; }
__device__ __forceinline__ float frn_sub(float a, float b) { float r = a - b; return r; }
__device__ __forceinline__ float frn_div(float a, float b) { float r = a / b; return r; }

// sq[n] = fl(fl(x0^2) + fl(x1^2))  (strict elementwise mul + 2-term reduce)
__device__ __forceinline__ float ref_sq(float x0, float x1) {
  return frn_add(frn_mul(x0, x0), frn_mul(x1, x1));
}
// dist_sq[n,m] = fl( fl(sq_n + sq_m) - 2*dot ), dot = fma(ny*my, fl(nx*mx)).
// 2*dot is exact, so fl(s - 2*dot) == fmaf(-2, dot, s) bitwise.
__device__ __forceinline__ float ref_key(float nx, float ny, float sqn,
                                         float mx, float my, float sqm) {
  float dot = fmaf(ny, my, frn_mul(nx, mx));
  float s = frn_add(sqn, sqm);
  return fmaf(-2.0f, dot, s);
}
// Monotone float->u32 (handles tiny-negative self-distance keys).
__device__ __forceinline__ unsigned int key_mono(float key) {
  int b = __float_as_int(key);
  return (unsigned int)b ^ (((unsigned int)(b >> 31)) | 0x80000000u);
}

// ---------------------------------------------------------------------------
// Weight transpose prep: wt[j*K + i] = w[i*N + j]
// ---------------------------------------------------------------------------
__global__ __launch_bounds__(256) void prep_w(
    const float* __restrict__ lw1, const float* __restrict__ lw2, const float* __restrict__ lw3,
    const float* __restrict__ cw1, const float* __restrict__ cw2,
    const float* __restrict__ tw1, const float* __restrict__ tw2,
    float* __restrict__ wt) {
  const int Ks[7]   = {2, 64, 128, 66, 128, 64, 128};
  const int Ns[7]   = {64, 128, 64, 128, 128, 128, 128};
  const int offs[7] = {0, 128, 8320, 16512, 24960, 41344, 49536};
  const float* srcs[7] = {lw1, lw2, lw3, cw1, cw2, tw1, tw2};
  int b = blockIdx.x;
  const float* src = srcs[b];
  float* dst = wt + offs[b];
  int K = Ks[b], N = Ns[b];
  for (int e = threadIdx.x; e < K * N; e += 256) {
    int j = e / K, i = e - j * K;
    dst[e] = src[i * N + j];
  }
}

// ---------------------------------------------------------------------------
// kNN scan: 1024 blocks = 128 point-groups x 8 candidate-slices.
// Branchless packed top-8 per slice: value = (mono(key) & 0xFFFFF000) | idx.
// Primary order = truncated ref key (bit-faithful to the reference's noisy
// f32 expanded-form key), tie -> lower idx. Exact re-rank happens in merge.
// ---------------------------------------------------------------------------
__global__ __launch_bounds__(256) void knn_scan(const float* __restrict__ x,
                                                unsigned int* __restrict__ ipart) {
  __shared__ float4 cand[QLEN];   // (cx, cy, sq, unused)
  int bx = blockIdx.x;
  int q = bx & (QN - 1);
  int pg = bx >> 3;                 // 0..127, 256 points each
  int batch = pg >> 4;              // 16 groups per batch
  const float* xb = x + (size_t)batch * NPTS * 2;
  int c0 = q * QLEN;
  for (int i = threadIdx.x; i < QLEN; i += 256) {
    float2 c = ((const float2*)xb)[c0 + i];
    cand[i] = make_float4(c.x, c.y, ref_sq(c.x, c.y), 0.f);
  }
  __syncthreads();
  int p = pg * 256 + threadIdx.x;   // global point id
  float2 me = ((const float2*)x)[p];
  float sqn = ref_sq(me.x, me.y);
  unsigned int d[SLOTS];
#pragma unroll
  for (int s = 0; s < SLOTS; s++) d[s] = 0xFFFFFFFFu;
  for (int m = 0; m < QLEN; m++) {
    float4 c = cand[m];
    float key = ref_key(me.x, me.y, sqn, c.x, c.y, c.z);
    unsigned int v = (key_mono(key) & 0xFFFFF000u) | (unsigned int)(c0 + m);
#pragma unroll
    for (int s = 0; s < SLOTS; s++) {
      unsigned int lo = min(v, d[s]);
      unsigned int hi = max(v, d[s]);
      d[s] = lo; v = hi;
    }
  }
  // layout: ipart[(q*SLOTS + s)*PTS + p]  (coalesced store & load)
#pragma unroll
  for (int s = 0; s < SLOTS; s++)
    ipart[((size_t)(q * SLOTS + s)) * PTS + p] = d[s];
}

// ---------------------------------------------------------------------------
// Merge: gather 64 packed candidates -> packed top-8 (branchless) -> exact
// (f32 ref key, idx) lex re-rank of the 8 survivors -> reference top-5.
// Then geometry (np-order f32 sums) + ssteqr/SLAEV2 replica as in R4.
// ---------------------------------------------------------------------------
__global__ __launch_bounds__(256) void merge_geom(const float* __restrict__ x,
    const unsigned int* __restrict__ ipart, float* __restrict__ lcct,
    float* __restrict__ angle_out, float* __restrict__ axes_out) {
  int p = blockIdx.x * 256 + threadIdx.x;
  int batch = p >> 12;
  const float2* xb = (const float2*)(x + (size_t)batch * NPTS * 2);
  float2 me = ((const float2*)x)[p];
  float sqn = ref_sq(me.x, me.y);

  // stage 1: packed top-8 of the 64 slice-survivors
  unsigned int g[SLOTS];
#pragma unroll
  for (int s = 0; s < SLOTS; s++) g[s] = 0xFFFFFFFFu;
  for (int qs = 0; qs < QN * SLOTS; qs++) {
    unsigned int v = ipart[(size_t)qs * PTS + p];
#pragma unroll
    for (int s = 0; s < SLOTS; s++) {
      unsigned int lo = min(v, g[s]);
      unsigned int hi = max(v, g[s]);
      g[s] = lo; v = hi;
    }
  }
  // stage 2: exact lex (key, idx) insertion of the 8 survivors into top-5
  float dk[5]; int id[5];
#pragma unroll
  for (int s = 0; s < 5; s++) { dk[s] = 3.0e38f; id[s] = 0x7fffffff; }
#pragma unroll
  for (int s8 = 0; s8 < SLOTS; s8++) {
    int ci = (int)(g[s8] & 0xFFFu);
    float2 c = xb[ci];
    float key = ref_key(me.x, me.y, sqn, c.x, c.y, ref_sq(c.x, c.y));
    float v = key; int vi = ci;
#pragma unroll
    for (int s = 0; s < 5; s++) {
      bool lt = (v < dk[s]) || (v == dk[s] && vi < id[s]);
      float tv = dk[s]; int ti = id[s];
      if (lt) { dk[s] = v; id[s] = vi; v = tv; vi = ti; }
    }
  }
  // rel, mean (np sequential order), centered
  float rx[5], ry[5];
  float sx = 0.f, sy = 0.f;
#pragma unroll
  for (int k = 0; k < 5; k++) {
    float2 nb = xb[id[k]];
    rx[k] = frn_sub(nb.x, me.x); ry[k] = frn_sub(nb.y, me.y);
    sx = frn_add(sx, rx[k]); sy = frn_add(sy, ry[k]);
  }
  float mx = frn_div(sx, 5.0f), my = frn_div(sy, 5.0f);
  float c00 = 0.f, c01 = 0.f, c11 = 0.f;
#pragma unroll
  for (int k = 0; k < 5; k++) {
    rx[k] = frn_sub(rx[k], mx); ry[k] = frn_sub(ry[k], my);
    c00 = frn_add(c00, frn_mul(rx[k], rx[k]));
    c01 = frn_add(c01, frn_mul(rx[k], ry[k]));
    c11 = frn_add(c11, frn_mul(ry[k], ry[k]));
  }
  c00 = frn_div(c00, 4.0f); c01 = frn_div(c01, 4.0f); c11 = frn_div(c11, 4.0f);
  float A = frn_add(c00, 1e-6f), Bv = c01, C = frn_add(c11, 1e-6f);

  // ---- ssteqr 2x2 replica ----
  float absA = fabsf(A), absC = fabsf(C), absB = fabsf(Bv);
  float thr = frn_mul(frn_mul(sqrtf(absA), sqrtf(absC)), EPS_L);
  bool diag = (absB == 0.f) || (absB <= thr);
  if (!diag) {
    bool qr = (absC < absA);
    float b2 = frn_mul(absB, absB);
    float t = qr ? frn_add(frn_mul(frn_mul(EPS2_L, absC), absA), SAFMIN_L)
                 : frn_add(frn_mul(frn_mul(EPS2_L, absA), absC), SAFMIN_L);
    if (b2 <= t) diag = true;
  }
  // v[:,0]=(v00,v10) (smaller eig e1), v[:,1]=(v01,v11) (larger eig e2)
  float e1, e2, v00, v10, v01, v11;
  if (diag) {
    if (C < A) { e1 = C; e2 = A; v00 = 0.f; v10 = 1.f; v01 = 1.f; v11 = 0.f; }
    else       { e1 = A; e2 = C; v00 = 1.f; v10 = 0.f; v01 = 0.f; v11 = 1.f; }
  } else {
    // ---- SLAEV2 replica ----
    float sm = frn_add(A, C), df = frn_sub(A, C);
    float adf = fabsf(df), tb = frn_add(Bv, Bv), ab = fabsf(tb);
    float rt;
    if (adf > ab) {
      float r = frn_div(ab, adf);
      rt = frn_mul(adf, sqrtf(frn_add(1.0f, frn_mul(r, r))));
    } else if (adf < ab) {
      float r = frn_div(adf, ab);
      rt = frn_mul(ab, sqrtf(frn_add(1.0f, frn_mul(r, r))));
    } else {
      rt = frn_mul(ab, sqrtf(2.0f));
    }
    float acmx, acmn;
    if (absA > absC) { acmx = A; acmn = C; } else { acmx = C; acmn = A; }
    float rt1, rt2; int sgn1;
    if (sm < 0.f) {
      rt1 = frn_mul(0.5f, frn_sub(sm, rt)); sgn1 = -1;
      rt2 = frn_sub(frn_mul(frn_div(acmx, rt1), acmn), frn_mul(frn_div(Bv, rt1), Bv));
    } else if (sm > 0.f) {
      rt1 = frn_mul(0.5f, frn_add(sm, rt)); sgn1 = 1;
      rt2 = frn_sub(frn_mul(frn_div(acmx, rt1), acmn), frn_mul(frn_div(Bv, rt1), Bv));
    } else {
      rt1 = frn_mul(0.5f, rt); rt2 = frn_mul(-0.5f, rt); sgn1 = 1;
    }
    float cs, cs1, sn1; int sgn2;
    if (df >= 0.f) { cs = frn_add(df, rt); sgn2 = 1; }
    else           { cs = frn_sub(df, rt); sgn2 = -1; }
    float acs = fabsf(cs);
    if (acs > ab) {
      float ct = frn_div(-tb, cs);
      sn1 = frn_div(1.0f, sqrtf(frn_add(1.0f, frn_mul(ct, ct))));
      cs1 = frn_mul(ct, sn1);
    } else {
      if (ab == 0.f) { cs1 = 1.0f; sn1 = 0.0f; }
      else {
        float tn = frn_div(-cs, tb);
        cs1 = frn_div(1.0f, sqrtf(frn_add(1.0f, frn_mul(tn, tn))));
        sn1 = frn_mul(tn, cs1);
      }
    }
    if (sgn1 == sgn2) { float t = cs1; cs1 = -sn1; sn1 = t; }
    if (rt2 < rt1) { e1 = rt2; e2 = rt1; v00 = -sn1; v10 = cs1; v01 = cs1;  v11 = sn1; }
    else           { e1 = rt1; e2 = rt2; v00 = cs1;  v10 = sn1; v01 = -sn1; v11 = cs1; }
  }

  angle_out[p] = atan2f(v11, v01);
  float aM = sqrtf(fmaxf(e2, 1e-6f));
  float am = sqrtf(fmaxf(e1, 1e-6f));
  float den = frn_add(fmaxf(aM, am), 1e-6f);
  axes_out[2 * p]     = fmaxf(frn_div(aM, den), 0.2f);
  axes_out[2 * p + 1] = fmaxf(frn_div(am, den), 0.2f);
  size_t row = (size_t)p * 5;
#pragma unroll
  for (int k = 0; k < 5; k++) {
    lcct[row + k]        = frn_add(frn_mul(rx[k], v00), frn_mul(ry[k], v10));
    lcct[ROWS + row + k] = frn_add(frn_mul(rx[k], v01), frn_mul(ry[k], v11));
  }
}

// ---------------------------------------------------------------------------
// Dense layer: thread-per-row, feature-major I/O (lane-coalesced),
// wave-uniform weight reads (scalar loads), 4 accumulators for ILP. ReLU.
// ---------------------------------------------------------------------------
template <int K, int NO>
__global__ __launch_bounds__(256) void dense_k(const float* __restrict__ in_t, int in_stride, int in_off,
                                               const float* __restrict__ wt, const float* __restrict__ bias,
                                               float* __restrict__ out_t, int out_stride,
                                               int M) {
  int r = blockIdx.x * 256 + threadIdx.x;
  if (r >= M) return;
  int per = NO / gridDim.y;
  int jlo = blockIdx.y * per, jhi = jlo + per;
  float in[K];
#pragma unroll
  for (int i = 0; i < K; i++) in[i] = in_t[(size_t)i * in_stride + in_off + r];
  for (int j = jlo; j < jhi; j += 4) {
    float acc0 = bias[j], acc1 = bias[j + 1], acc2 = bias[j + 2], acc3 = bias[j + 3];
    const float* w0 = wt + (size_t)j * K;
#pragma unroll
    for (int i = 0; i < K; i++) {
      float xi = in[i];
      acc0 = fmaf(xi, w0[i], acc0);
      acc1 = fmaf(xi, w0[K + i], acc1);
      acc2 = fmaf(xi, w0[2 * K + i], acc2);
      acc3 = fmaf(xi, w0[3 * K + i], acc3);
    }
    out_t[(size_t)j * out_stride + r]       = fmaxf(acc0, 0.f);
    out_t[(size_t)(j + 1) * out_stride + r] = fmaxf(acc1, 0.f);
    out_t[(size_t)(j + 2) * out_stride + r] = fmaxf(acc2, 0.f);
    out_t[(size_t)(j + 3) * out_stride + r] = fmaxf(acc3, 0.f);
  }
}

// ---------------------------------------------------------------------------
// Max over K=5 rows -> lftx rows 2..65 ; rows 0..1 = x passthrough.
// ---------------------------------------------------------------------------
__global__ __launch_bounds__(256) void maxpack(const float* __restrict__ h3, int rows_c, int p_shift, int pbase,
                                               const float* __restrict__ x, float* __restrict__ lftx) {
  int idx = blockIdx.x * 256 + threadIdx.x;
  int pts_c = 1 << p_shift;
  int f = idx >> p_shift;
  int pl = idx & (pts_c - 1);
  int p = pbase + pl;
  if (f < 64) {
    const float* hr = h3 + (size_t)f * rows_c + (size_t)pl * 5;
    float m = fmaxf(fmaxf(fmaxf(hr[0], hr[1]), fmaxf(hr[2], hr[3])), hr[4]);
    lftx[(size_t)(f + 2) * PTS + p] = m;
  } else if (f < 66) {
    int i = f - 64;
    lftx[(size_t)i * PTS + p] = x[(size_t)p * 2 + i];
  }
}

// ---------------------------------------------------------------------------
// Transpose [256][32768] feature-major head outputs into d_out row-major.
// ---------------------------------------------------------------------------
__global__ __launch_bounds__(256) void transpose_out(const float* __restrict__ o_t, float* __restrict__ out) {
  __shared__ float tile[64][65];
  int p0 = blockIdx.x * 64;
  int j0 = blockIdx.y * 64;
  int tc = threadIdx.x & 63, tr = threadIdx.x >> 6;
#pragma unroll
  for (int rr = 0; rr < 16; rr++) {
    int j = tr + rr * 4;
    tile[j][tc] = o_t[(size_t)(j0 + j) * PTS + p0 + tc];
  }
  __syncthreads();
#pragma unroll
  for (int rr = 0; rr < 16; rr++) {
    int pl = tr + rr * 4;
    int p = p0 + pl;
    int j = j0 + tc;
    float v = tile[tc][pl];
    size_t o = (j < 128) ? ((size_t)p * 128 + j)
                         : ((size_t)4194304 + (size_t)p * 128 + (j - 128));
    out[o] = v;
  }
}

// ---------------------------------------------------------------------------
extern "C" void kernel_launch(void* const* d_in, const int* in_sizes, int n_in,
                              void* d_out, int out_size, void* d_ws, size_t ws_size,
                              hipStream_t stream) {
  const float* x   = (const float*)d_in[0];
  const float* lb1 = (const float*)d_in[2];
  const float* lb2 = (const float*)d_in[4];
  const float* lb3 = (const float*)d_in[6];
  const float* cb1 = (const float*)d_in[8];
  const float* cb2 = (const float*)d_in[10];
  const float* tb1 = (const float*)d_in[12];
  const float* tb2 = (const float*)d_in[14];

  float* out = (float*)d_out;
  float* angle_out = out + 8388608;   // after cls(4194304)+topo(4194304)
  float* axes_out  = out + 8421376;

  float* W = (float*)d_ws;
  // Segment A (phase-overlapped): knn ipart (QN*SLOTS*PTS = 2M u32) lives at
  // W+0 and is dead before the heads reuse the region.
  float* outct = W + 0;              // 128*PTS
  float* outtt = W + 4194304;        // 128*PTS (contiguous with outct)
  float* a1    = W + 8388608;        // 128*PTS
  const size_t segA = 12582912;
  float* lftx = W + segA;                      // 66*PTS = 2162688
  float* lcct = W + segA + 2162688;            // 2*ROWS = 327680
  float* wt   = W + segA + 2162688 + 327680;   // 65920
  float* hbuf = wt + 65920;
  size_t fixed_f = (size_t)(hbuf - W);

  int chunks = 16;
  const int copts[5] = {1, 2, 4, 8, 16};
  for (int ci = 0; ci < 5; ci++) {
    size_t need = (fixed_f + (size_t)(ROWS / copts[ci]) * 256) * sizeof(float);
    if (need <= ws_size) { chunks = copts[ci]; break; }
  }
  int rows_c = ROWS / chunks;
  int pts_c  = PTS / chunks;
  int p_shift = 31 - __builtin_clz((unsigned)pts_c);

  float* h1 = hbuf;
  float* h2 = hbuf + (size_t)rows_c * 64;
  float* h3 = hbuf + (size_t)rows_c * 192;

  prep_w<<<7, 256, 0, stream>>>((const float*)d_in[1], (const float*)d_in[3], (const float*)d_in[5],
                                (const float*)d_in[7], (const float*)d_in[9],
                                (const float*)d_in[11], (const float*)d_in[13], wt);
  knn_scan<<<1024, 256, 0, stream>>>(x, (unsigned int*)W);
  merge_geom<<<128, 256, 0, stream>>>(x, (const unsigned int*)W, lcct, angle_out, axes_out);

  for (int c = 0; c < chunks; c++) {
    int row0 = c * rows_c;
    dense_k<2, 64><<<dim3(rows_c / 256, 1), 256, 0, stream>>>(lcct, ROWS, row0, wt + 0, lb1, h1, rows_c, rows_c);
    dense_k<64, 128><<<dim3(rows_c / 256, 1), 256, 0, stream>>>(h1, rows_c, 0, wt + 128, lb2, h2, rows_c, rows_c);
    dense_k<128, 64><<<dim3(rows_c / 256, 1), 256, 0, stream>>>(h2, rows_c, 0, wt + 8320, lb3, h3, rows_c, rows_c);
    maxpack<<<(66 * pts_c) / 256, 256, 0, stream>>>(h3, rows_c, p_shift, c * pts_c, x, lftx);
  }

  dense_k<66, 128><<<dim3(PTS / 256, 4), 256, 0, stream>>>(lftx, PTS, 0, wt + 16512, cb1, a1, PTS, PTS);
  dense_k<128, 128><<<dim3(PTS / 256, 4), 256, 0, stream>>>(a1, PTS, 0, wt + 24960, cb2, outct, PTS, PTS);
  dense_k<64, 128><<<dim3(PTS / 256, 4), 256, 0, stream>>>(lftx + 2 * PTS, PTS, 0, wt + 41344, tb1, a1, PTS, PTS);
  dense_k<128, 128><<<dim3(PTS / 256, 4), 256, 0, stream>>>(a1, PTS, 0, wt + 49536, tb2, outtt, PTS, PTS);

  transpose_out<<<dim3(512, 4), 256, 0, stream>>>(outct, out);
}

// Round 6
// 533.292 us; speedup vs baseline: 1.5107x; 1.0177x over previous
//
#include <hip/hip_runtime.h>
#include <math.h>

#pragma clang fp contract(off)

#define NPTS 4096
#define PTS  32768
#define ROWS 163840   // PTS * 5
#define QN   8        // candidate slices per batch
#define QLEN 512      // NPTS / QN
#define SLOTS 8       // packed top-k slots per slice (and global survivors)

// LAPACK single-precision machine constants (gfortran/IEEE):
#define EPS_L   5.9604644775390625e-8f    // 2^-24  SLAMCH('E')
#define EPS2_L  3.5527136788005009e-15f   // 2^-48
#define SAFMIN_L 1.1754943508222875e-38f  // 2^-126

// Round-to-nearest, non-contractible f32 ops (file pragma disables fusion).
__device__ __forceinline__ float frn_mul(float a, float b) { float r = a * b; return r; }
__device__ __forceinline__ float frn_add(float a, float b) { float r = a + b; return r; }
__device__ __forceinline__ float frn_sub(float a, float b) { float r = a - b; return r; }
__device__ __forceinline__ float frn_div(float a, float b) { float r = a / b; return r; }

// sq[n] = fl(fl(x0^2) + fl(x1^2))  (strict elementwise mul + 2-term reduce)
__device__ __forceinline__ float ref_sq(float x0, float x1) {
  return frn_add(frn_mul(x0, x0), frn_mul(x1, x1));
}
// dist_sq[n,m] = fl( fl(sq_n + sq_m) - 2*dot ), dot = fma(ny*my, fl(nx*mx)).
// 2*dot is exact, so fl(s - 2*dot) == fmaf(-2, dot, s) bitwise.
__device__ __forceinline__ float ref_key(float nx, float ny, float sqn,
                                         float mx, float my, float sqm) {
  float dot = fmaf(ny, my, frn_mul(nx, mx));
  float s = frn_add(sqn, sqm);
  return fmaf(-2.0f, dot, s);
}
// Monotone float->u32 (handles tiny-negative self-distance keys).
__device__ __forceinline__ unsigned int key_mono(float key) {
  int b = __float_as_int(key);
  return (unsigned int)b ^ (((unsigned int)(b >> 31)) | 0x80000000u);
}

// ---------------------------------------------------------------------------
// Weight transpose prep: wt[j*K + i] = w[i*N + j]
// ---------------------------------------------------------------------------
__global__ __launch_bounds__(256) void prep_w(
    const float* __restrict__ lw1, const float* __restrict__ lw2, const float* __restrict__ lw3,
    const float* __restrict__ cw1, const float* __restrict__ cw2,
    const float* __restrict__ tw1, const float* __restrict__ tw2,
    float* __restrict__ wt) {
  const int Ks[7]   = {2, 64, 128, 66, 128, 64, 128};
  const int Ns[7]   = {64, 128, 64, 128, 128, 128, 128};
  const int offs[7] = {0, 128, 8320, 16512, 24960, 41344, 49536};
  const float* srcs[7] = {lw1, lw2, lw3, cw1, cw2, tw1, tw2};
  int b = blockIdx.x;
  const float* src = srcs[b];
  float* dst = wt + offs[b];
  int K = Ks[b], N = Ns[b];
  for (int e = threadIdx.x; e < K * N; e += 256) {
    int j = e / K, i = e - j * K;
    dst[e] = src[i * N + j];
  }
}

// ---------------------------------------------------------------------------
// kNN scan: 1024 blocks = 128 point-groups x 8 candidate-slices.
// Branchless packed top-8 per slice: value = (mono(key) & 0xFFFFF000) | idx.
// ---------------------------------------------------------------------------
__global__ __launch_bounds__(256) void knn_scan(const float* __restrict__ x,
                                                unsigned int* __restrict__ ipart) {
  __shared__ float4 cand[QLEN];   // (cx, cy, sq, unused)
  int bx = blockIdx.x;
  int q = bx & (QN - 1);
  int pg = bx >> 3;                 // 0..127, 256 points each
  int batch = pg >> 4;              // 16 groups per batch
  const float* xb = x + (size_t)batch * NPTS * 2;
  int c0 = q * QLEN;
  for (int i = threadIdx.x; i < QLEN; i += 256) {
    float2 c = ((const float2*)xb)[c0 + i];
    cand[i] = make_float4(c.x, c.y, ref_sq(c.x, c.y), 0.f);
  }
  __syncthreads();
  int p = pg * 256 + threadIdx.x;   // global point id
  float2 me = ((const float2*)x)[p];
  float sqn = ref_sq(me.x, me.y);
  unsigned int d[SLOTS];
#pragma unroll
  for (int s = 0; s < SLOTS; s++) d[s] = 0xFFFFFFFFu;
  for (int m = 0; m < QLEN; m++) {
    float4 c = cand[m];
    float key = ref_key(me.x, me.y, sqn, c.x, c.y, c.z);
    unsigned int v = (key_mono(key) & 0xFFFFF000u) | (unsigned int)(c0 + m);
#pragma unroll
    for (int s = 0; s < SLOTS; s++) {
      unsigned int lo = min(v, d[s]);
      unsigned int hi = max(v, d[s]);
      d[s] = lo; v = hi;
    }
  }
#pragma unroll
  for (int s = 0; s < SLOTS; s++)
    ipart[((size_t)(q * SLOTS + s)) * PTS + p] = d[s];
}

// ---------------------------------------------------------------------------
// Merge + geometry + FUSED local layer 1 (K=2 -> 64, ReLU), h1 feature-major.
// ---------------------------------------------------------------------------
__global__ __launch_bounds__(256) void merge_geom(const float* __restrict__ x,
    const unsigned int* __restrict__ ipart,
    const float* __restrict__ lw1t, const float* __restrict__ lb1,
    float* __restrict__ h1,
    float* __restrict__ angle_out, float* __restrict__ axes_out) {
  int p = blockIdx.x * 256 + threadIdx.x;
  int batch = p >> 12;
  const float2* xb = (const float2*)(x + (size_t)batch * NPTS * 2);
  float2 me = ((const float2*)x)[p];
  float sqn = ref_sq(me.x, me.y);

  // stage 1: packed top-8 of the 64 slice-survivors
  unsigned int g[SLOTS];
#pragma unroll
  for (int s = 0; s < SLOTS; s++) g[s] = 0xFFFFFFFFu;
  for (int qs = 0; qs < QN * SLOTS; qs++) {
    unsigned int v = ipart[(size_t)qs * PTS + p];
#pragma unroll
    for (int s = 0; s < SLOTS; s++) {
      unsigned int lo = min(v, g[s]);
      unsigned int hi = max(v, g[s]);
      g[s] = lo; v = hi;
    }
  }
  // stage 2: exact lex (key, idx) re-rank of the 8 survivors into top-5
  float dk[5]; int id[5];
#pragma unroll
  for (int s = 0; s < 5; s++) { dk[s] = 3.0e38f; id[s] = 0x7fffffff; }
#pragma unroll
  for (int s8 = 0; s8 < SLOTS; s8++) {
    int ci = (int)(g[s8] & 0xFFFu);
    float2 c = xb[ci];
    float key = ref_key(me.x, me.y, sqn, c.x, c.y, ref_sq(c.x, c.y));
    float v = key; int vi = ci;
#pragma unroll
    for (int s = 0; s < 5; s++) {
      bool lt = (v < dk[s]) || (v == dk[s] && vi < id[s]);
      float tv = dk[s]; int ti = id[s];
      if (lt) { dk[s] = v; id[s] = vi; v = tv; vi = ti; }
    }
  }
  // rel, mean (np sequential order), centered
  float rx[5], ry[5];
  float sx = 0.f, sy = 0.f;
#pragma unroll
  for (int k = 0; k < 5; k++) {
    float2 nb = xb[id[k]];
    rx[k] = frn_sub(nb.x, me.x); ry[k] = frn_sub(nb.y, me.y);
    sx = frn_add(sx, rx[k]); sy = frn_add(sy, ry[k]);
  }
  float mx = frn_div(sx, 5.0f), my = frn_div(sy, 5.0f);
  float c00 = 0.f, c01 = 0.f, c11 = 0.f;
#pragma unroll
  for (int k = 0; k < 5; k++) {
    rx[k] = frn_sub(rx[k], mx); ry[k] = frn_sub(ry[k], my);
    c00 = frn_add(c00, frn_mul(rx[k], rx[k]));
    c01 = frn_add(c01, frn_mul(rx[k], ry[k]));
    c11 = frn_add(c11, frn_mul(ry[k], ry[k]));
  }
  c00 = frn_div(c00, 4.0f); c01 = frn_div(c01, 4.0f); c11 = frn_div(c11, 4.0f);
  float A = frn_add(c00, 1e-6f), Bv = c01, C = frn_add(c11, 1e-6f);

  // ---- ssteqr 2x2 replica ----
  float absA = fabsf(A), absC = fabsf(C), absB = fabsf(Bv);
  float thr = frn_mul(frn_mul(sqrtf(absA), sqrtf(absC)), EPS_L);
  bool diag = (absB == 0.f) || (absB <= thr);
  if (!diag) {
    bool qr = (absC < absA);
    float b2 = frn_mul(absB, absB);
    float t = qr ? frn_add(frn_mul(frn_mul(EPS2_L, absC), absA), SAFMIN_L)
                 : frn_add(frn_mul(frn_mul(EPS2_L, absA), absC), SAFMIN_L);
    if (b2 <= t) diag = true;
  }
  // v[:,0]=(v00,v10) (smaller eig e1), v[:,1]=(v01,v11) (larger eig e2)
  float e1, e2, v00, v10, v01, v11;
  if (diag) {
    if (C < A) { e1 = C; e2 = A; v00 = 0.f; v10 = 1.f; v01 = 1.f; v11 = 0.f; }
    else       { e1 = A; e2 = C; v00 = 1.f; v10 = 0.f; v01 = 0.f; v11 = 1.f; }
  } else {
    // ---- SLAEV2 replica ----
    float sm = frn_add(A, C), df = frn_sub(A, C);
    float adf = fabsf(df), tb = frn_add(Bv, Bv), ab = fabsf(tb);
    float rt;
    if (adf > ab) {
      float r = frn_div(ab, adf);
      rt = frn_mul(adf, sqrtf(frn_add(1.0f, frn_mul(r, r))));
    } else if (adf < ab) {
      float r = frn_div(adf, ab);
      rt = frn_mul(ab, sqrtf(frn_add(1.0f, frn_mul(r, r))));
    } else {
      rt = frn_mul(ab, sqrtf(2.0f));
    }
    float acmx, acmn;
    if (absA > absC) { acmx = A; acmn = C; } else { acmx = C; acmn = A; }
    float rt1, rt2; int sgn1;
    if (sm < 0.f) {
      rt1 = frn_mul(0.5f, frn_sub(sm, rt)); sgn1 = -1;
      rt2 = frn_sub(frn_mul(frn_div(acmx, rt1), acmn), frn_mul(frn_div(Bv, rt1), Bv));
    } else if (sm > 0.f) {
      rt1 = frn_mul(0.5f, frn_add(sm, rt)); sgn1 = 1;
      rt2 = frn_sub(frn_mul(frn_div(acmx, rt1), acmn), frn_mul(frn_div(Bv, rt1), Bv));
    } else {
      rt1 = frn_mul(0.5f, rt); rt2 = frn_mul(-0.5f, rt); sgn1 = 1;
    }
    float cs, cs1, sn1; int sgn2;
    if (df >= 0.f) { cs = frn_add(df, rt); sgn2 = 1; }
    else           { cs = frn_sub(df, rt); sgn2 = -1; }
    float acs = fabsf(cs);
    if (acs > ab) {
      float ct = frn_div(-tb, cs);
      sn1 = frn_div(1.0f, sqrtf(frn_add(1.0f, frn_mul(ct, ct))));
      cs1 = frn_mul(ct, sn1);
    } else {
      if (ab == 0.f) { cs1 = 1.0f; sn1 = 0.0f; }
      else {
        float tn = frn_div(-cs, tb);
        cs1 = frn_div(1.0f, sqrtf(frn_add(1.0f, frn_mul(tn, tn))));
        sn1 = frn_mul(tn, cs1);
      }
    }
    if (sgn1 == sgn2) { float t = cs1; cs1 = -sn1; sn1 = t; }
    if (rt2 < rt1) { e1 = rt2; e2 = rt1; v00 = -sn1; v10 = cs1; v01 = cs1;  v11 = sn1; }
    else           { e1 = rt1; e2 = rt2; v00 = cs1;  v10 = sn1; v01 = -sn1; v11 = cs1; }
  }

  angle_out[p] = atan2f(v11, v01);
  float aM = sqrtf(fmaxf(e2, 1e-6f));
  float am = sqrtf(fmaxf(e1, 1e-6f));
  float den = frn_add(fmaxf(aM, am), 1e-6f);
  axes_out[2 * p]     = fmaxf(frn_div(aM, den), 0.2f);
  axes_out[2 * p + 1] = fmaxf(frn_div(am, den), 0.2f);

  // ---- fused local layer 1: h1[f][p*5+k] = relu(lcc0*wa + lcc1*wb + b) ----
  float l0[5], l1v[5];
#pragma unroll
  for (int k = 0; k < 5; k++) {
    l0[k]  = frn_add(frn_mul(rx[k], v00), frn_mul(ry[k], v10));
    l1v[k] = frn_add(frn_mul(rx[k], v01), frn_mul(ry[k], v11));
  }
  size_t rowb = (size_t)p * 5;
  for (int f = 0; f < 64; ++f) {
    float wa = lw1t[f * 2], wb = lw1t[f * 2 + 1], bb = lb1[f];
#pragma unroll
    for (int k = 0; k < 5; k++) {
      float h = fmaf(l1v[k], wb, fmaf(l0[k], wa, bb));
      h1[(size_t)f * ROWS + rowb + k] = fmaxf(h, 0.f);
    }
  }
}

// ---------------------------------------------------------------------------
// Dense layer, LDS-staged inputs. Tile = 128 rows (feature-major in LDS,
// conflict-free), 256 threads = 128 rows x 2 j-halves (readfirstlane pins
// the half so weight addresses stay wave-uniform -> s_load). 8 accumulators.
// NOB = outputs per block (blockIdx.y splits the full NO range).
// ---------------------------------------------------------------------------
template <int K, int NOB>
__global__ __launch_bounds__(256) void dense_lds(const float* __restrict__ in_t, int M,
                                                 const float* __restrict__ wt,
                                                 const float* __restrict__ bias,
                                                 float* __restrict__ out_t) {
  __shared__ float tile[K * 128];
  int r0 = blockIdx.x * 128;
  for (int e = threadIdx.x; e < K * 128; e += 256) {
    int i = e >> 7, rr = e & 127;
    tile[e] = in_t[(size_t)i * M + r0 + rr];
  }
  __syncthreads();
  int r = threadIdx.x & 127;
  int jhalf = __builtin_amdgcn_readfirstlane((int)(threadIdx.x >> 7));
  const int JT = NOB / 2;   // outputs per thread
  int jbase = blockIdx.y * NOB + jhalf * JT;
  for (int jj = 0; jj < JT; jj += 8) {
    const float* w0 = wt + (size_t)(jbase + jj) * K;
    float acc[8];
#pragma unroll
    for (int u = 0; u < 8; u++) acc[u] = bias[jbase + jj + u];
    for (int i = 0; i < K; ++i) {
      float xi = tile[i * 128 + r];
#pragma unroll
      for (int u = 0; u < 8; u++)
        acc[u] = fmaf(xi, w0[(size_t)u * K + i], acc[u]);
    }
#pragma unroll
    for (int u = 0; u < 8; u++)
      out_t[(size_t)(jbase + jj + u) * M + r0 + r] = fmaxf(acc[u], 0.f);
  }
}

// ---------------------------------------------------------------------------
// Max over K=5 rows -> lftx rows 2..65 ; rows 0..1 = x passthrough.
// ---------------------------------------------------------------------------
__global__ __launch_bounds__(256) void maxpack(const float* __restrict__ h3,
                                               const float* __restrict__ x,
                                               float* __restrict__ lftx) {
  int idx = blockIdx.x * 256 + threadIdx.x;
  int f = idx >> 15;
  int p = idx & (PTS - 1);
  if (f < 64) {
    const float* hr = h3 + (size_t)f * ROWS + (size_t)p * 5;
    float m = fmaxf(fmaxf(fmaxf(hr[0], hr[1]), fmaxf(hr[2], hr[3])), hr[4]);
    lftx[(size_t)(f + 2) * PTS + p] = m;
  } else if (f < 66) {
    int i = f - 64;
    lftx[(size_t)i * PTS + p] = x[(size_t)p * 2 + i];
  }
}

// ---------------------------------------------------------------------------
// Transpose [256][32768] feature-major head outputs into d_out row-major.
// ---------------------------------------------------------------------------
__global__ __launch_bounds__(256) void transpose_out(const float* __restrict__ o_t, float* __restrict__ out) {
  __shared__ float tile[64][65];
  int p0 = blockIdx.x * 64;
  int j0 = blockIdx.y * 64;
  int tc = threadIdx.x & 63, tr = threadIdx.x >> 6;
#pragma unroll
  for (int rr = 0; rr < 16; rr++) {
    int j = tr + rr * 4;
    tile[j][tc] = o_t[(size_t)(j0 + j) * PTS + p0 + tc];
  }
  __syncthreads();
#pragma unroll
  for (int rr = 0; rr < 16; rr++) {
    int pl = tr + rr * 4;
    int p = p0 + pl;
    int j = j0 + tc;
    float v = tile[tc][pl];
    size_t o = (j < 128) ? ((size_t)p * 128 + j)
                         : ((size_t)4194304 + (size_t)p * 128 + (j - 128));
    out[o] = v;
  }
}

// ---------------------------------------------------------------------------
extern "C" void kernel_launch(void* const* d_in, const int* in_sizes, int n_in,
                              void* d_out, int out_size, void* d_ws, size_t ws_size,
                              hipStream_t stream) {
  const float* x   = (const float*)d_in[0];
  const float* lb1 = (const float*)d_in[2];
  const float* lb2 = (const float*)d_in[4];
  const float* lb3 = (const float*)d_in[6];
  const float* cb1 = (const float*)d_in[8];
  const float* cb2 = (const float*)d_in[10];
  const float* tb1 = (const float*)d_in[12];
  const float* tb2 = (const float*)d_in[14];

  float* out = (float*)d_out;
  float* angle_out = out + 8388608;   // after cls(4194304)+topo(4194304)
  float* axes_out  = out + 8421376;

  // Workspace layout (floats), lifetime-overlapped regions:
  //   wt   [66048]
  //   R1   [10485760]  ipart (knn->merge) then h3 (l3->maxpack)
  //   R2   [10485760]  h1 (merge->l2) then a1 (c1->c2) then a1 (t1->t2)
  //   R3   [20971520]  h2 (l2->l3) then outct+outtt (heads->transpose)
  //   lftx [2162688]
  // total = 44,171,776 floats = 176.7 MB (R5 proved >= 228 MB available)
  float* W = (float*)d_ws;
  float* wt   = W;
  float* R1   = W + 66048;
  float* R2   = R1 + 10485760;
  float* R3   = R2 + 10485760;
  float* lftx = R3 + 20971520;
  unsigned int* ipart = (unsigned int*)R1;
  float* h3    = R1;
  float* h1    = R2;
  float* a1    = R2;
  float* h2    = R3;
  float* outct = R3;
  float* outtt = R3 + 4194304;

  prep_w<<<7, 256, 0, stream>>>((const float*)d_in[1], (const float*)d_in[3], (const float*)d_in[5],
                                (const float*)d_in[7], (const float*)d_in[9],
                                (const float*)d_in[11], (const float*)d_in[13], wt);
  knn_scan<<<1024, 256, 0, stream>>>(x, ipart);
  merge_geom<<<128, 256, 0, stream>>>(x, ipart, wt + 0, lb1, h1, angle_out, axes_out);

  // local MLP layers 2,3 over 163840 rows
  dense_lds<64, 128><<<dim3(ROWS / 128, 1), 256, 0, stream>>>(h1, ROWS, wt + 128, lb2, h2);
  dense_lds<128, 64><<<dim3(ROWS / 128, 1), 256, 0, stream>>>(h2, ROWS, wt + 8320, lb3, h3);
  maxpack<<<(66 * PTS) / 256, 256, 0, stream>>>(h3, x, lftx);

  // heads over 32768 rows (j split across blockIdx.y)
  dense_lds<66, 64><<<dim3(PTS / 128, 2), 256, 0, stream>>>(lftx, PTS, wt + 16512, cb1, a1);
  dense_lds<128, 64><<<dim3(PTS / 128, 2), 256, 0, stream>>>(a1, PTS, wt + 24960, cb2, outct);
  dense_lds<64, 64><<<dim3(PTS / 128, 2), 256, 0, stream>>>(lftx + 2 * PTS, PTS, wt + 41344, tb1, a1);
  dense_lds<128, 64><<<dim3(PTS / 128, 2), 256, 0, stream>>>(a1, PTS, wt + 49536, tb2, outtt);

  transpose_out<<<dim3(512, 4), 256, 0, stream>>>(outct, out);
}

// Round 7
// 413.582 us; speedup vs baseline: 1.9480x; 1.2894x over previous
//
#include <hip/hip_runtime.h>
#include <math.h>

#pragma clang fp contract(off)

#define NPTS 4096
#define PTS  32768
#define ROWS 163840   // PTS * 5
#define QN   8        // candidate slices per batch
#define QLEN 512      // NPTS / QN
#define SLOTS 8       // packed top-k slots per slice (and global survivors)

// LAPACK single-precision machine constants (gfortran/IEEE):
#define EPS_L   5.9604644775390625e-8f    // 2^-24  SLAMCH('E')
#define EPS2_L  3.5527136788005009e-15f   // 2^-48
#define SAFMIN_L 1.1754943508222875e-38f  // 2^-126

// Round-to-nearest, non-contractible f32 ops (file pragma disables fusion).
__device__ __forceinline__ float frn_mul(float a, float b) { float r = a * b; return r; }
__device__ __forceinline__ float frn_add(float a, float b) { float r = a + b; return r; }
__device__ __forceinline__ float frn_sub(float a, float b) { float r = a - b; return r; }
__device__ __forceinline__ float frn_div(float a, float b) { float r = a / b; return r; }

__device__ __forceinline__ float ref_sq(float x0, float x1) {
  return frn_add(frn_mul(x0, x0), frn_mul(x1, x1));
}
// dist_sq[n,m] = fl( fl(sq_n + sq_m) - 2*dot ), dot = fma(ny*my, fl(nx*mx)).
__device__ __forceinline__ float ref_key(float nx, float ny, float sqn,
                                         float mx, float my, float sqm) {
  float dot = fmaf(ny, my, frn_mul(nx, mx));
  float s = frn_add(sqn, sqm);
  return fmaf(-2.0f, dot, s);
}
__device__ __forceinline__ unsigned int key_mono(float key) {
  int b = __float_as_int(key);
  return (unsigned int)b ^ (((unsigned int)(b >> 31)) | 0x80000000u);
}

// ---------------------------------------------------------------------------
// Weight transpose prep, zero-padded K stride: wt[j*Kp + i] = (i<K)? w[i*N+j]:0
// ---------------------------------------------------------------------------
__global__ __launch_bounds__(256) void prep_w(
    const float* __restrict__ lw1, const float* __restrict__ lw2, const float* __restrict__ lw3,
    const float* __restrict__ cw1, const float* __restrict__ cw2,
    const float* __restrict__ tw1, const float* __restrict__ tw2,
    float* __restrict__ wt) {
  const int Ks[7]   = {2, 64, 128, 66, 128, 64, 128};
  const int Kp[7]   = {2, 64, 128, 80, 128, 64, 128};
  const int Ns[7]   = {64, 128, 64, 128, 128, 128, 128};
  const int offs[7] = {0, 128, 8320, 16512, 26752, 43136, 51328};
  const float* srcs[7] = {lw1, lw2, lw3, cw1, cw2, tw1, tw2};
  int b = blockIdx.x;
  const float* src = srcs[b];
  float* dst = wt + offs[b];
  int K = Ks[b], KP = Kp[b], N = Ns[b];
  for (int e = threadIdx.x; e < KP * N; e += 256) {
    int j = e / KP, i = e - j * KP;
    dst[e] = (i < K) ? src[i * N + j] : 0.0f;
  }
}

// ---------------------------------------------------------------------------
// kNN scan: 1024 blocks = 128 point-groups x 8 candidate-slices.
// Branchless packed top-8 per slice: value = (mono(key) & 0xFFFFF000) | idx.
// ---------------------------------------------------------------------------
__global__ __launch_bounds__(256) void knn_scan(const float* __restrict__ x,
                                                unsigned int* __restrict__ ipart) {
  __shared__ float4 cand[QLEN];
  int bx = blockIdx.x;
  int q = bx & (QN - 1);
  int pg = bx >> 3;
  int batch = pg >> 4;
  const float* xb = x + (size_t)batch * NPTS * 2;
  int c0 = q * QLEN;
  for (int i = threadIdx.x; i < QLEN; i += 256) {
    float2 c = ((const float2*)xb)[c0 + i];
    cand[i] = make_float4(c.x, c.y, ref_sq(c.x, c.y), 0.f);
  }
  __syncthreads();
  int p = pg * 256 + threadIdx.x;
  float2 me = ((const float2*)x)[p];
  float sqn = ref_sq(me.x, me.y);
  unsigned int d[SLOTS];
#pragma unroll
  for (int s = 0; s < SLOTS; s++) d[s] = 0xFFFFFFFFu;
  for (int m = 0; m < QLEN; m++) {
    float4 c = cand[m];
    float key = ref_key(me.x, me.y, sqn, c.x, c.y, c.z);
    unsigned int v = (key_mono(key) & 0xFFFFF000u) | (unsigned int)(c0 + m);
#pragma unroll
    for (int s = 0; s < SLOTS; s++) {
      unsigned int lo = min(v, d[s]);
      unsigned int hi = max(v, d[s]);
      d[s] = lo; v = hi;
    }
  }
#pragma unroll
  for (int s = 0; s < SLOTS; s++)
    ipart[((size_t)(q * SLOTS + s)) * PTS + p] = d[s];
}

// ---------------------------------------------------------------------------
// Merge + geometry + FUSED local layer 1 (K=2 -> 64, ReLU), h1 feature-major.
// ---------------------------------------------------------------------------
__global__ __launch_bounds__(256) void merge_geom(const float* __restrict__ x,
    const unsigned int* __restrict__ ipart,
    const float* __restrict__ lw1t, const float* __restrict__ lb1,
    float* __restrict__ h1,
    float* __restrict__ angle_out, float* __restrict__ axes_out) {
  int p = blockIdx.x * 256 + threadIdx.x;
  int batch = p >> 12;
  const float2* xb = (const float2*)(x + (size_t)batch * NPTS * 2);
  float2 me = ((const float2*)x)[p];
  float sqn = ref_sq(me.x, me.y);

  unsigned int g[SLOTS];
#pragma unroll
  for (int s = 0; s < SLOTS; s++) g[s] = 0xFFFFFFFFu;
  for (int qs = 0; qs < QN * SLOTS; qs++) {
    unsigned int v = ipart[(size_t)qs * PTS + p];
#pragma unroll
    for (int s = 0; s < SLOTS; s++) {
      unsigned int lo = min(v, g[s]);
      unsigned int hi = max(v, g[s]);
      g[s] = lo; v = hi;
    }
  }
  float dk[5]; int id[5];
#pragma unroll
  for (int s = 0; s < 5; s++) { dk[s] = 3.0e38f; id[s] = 0x7fffffff; }
#pragma unroll
  for (int s8 = 0; s8 < SLOTS; s8++) {
    int ci = (int)(g[s8] & 0xFFFu);
    float2 c = xb[ci];
    float key = ref_key(me.x, me.y, sqn, c.x, c.y, ref_sq(c.x, c.y));
    float v = key; int vi = ci;
#pragma unroll
    for (int s = 0; s < 5; s++) {
      bool lt = (v < dk[s]) || (v == dk[s] && vi < id[s]);
      float tv = dk[s]; int ti = id[s];
      if (lt) { dk[s] = v; id[s] = vi; v = tv; vi = ti; }
    }
  }
  float rx[5], ry[5];
  float sx = 0.f, sy = 0.f;
#pragma unroll
  for (int k = 0; k < 5; k++) {
    float2 nb = xb[id[k]];
    rx[k] = frn_sub(nb.x, me.x); ry[k] = frn_sub(nb.y, me.y);
    sx = frn_add(sx, rx[k]); sy = frn_add(sy, ry[k]);
  }
  float mx = frn_div(sx, 5.0f), my = frn_div(sy, 5.0f);
  float c00 = 0.f, c01 = 0.f, c11 = 0.f;
#pragma unroll
  for (int k = 0; k < 5; k++) {
    rx[k] = frn_sub(rx[k], mx); ry[k] = frn_sub(ry[k], my);
    c00 = frn_add(c00, frn_mul(rx[k], rx[k]));
    c01 = frn_add(c01, frn_mul(rx[k], ry[k]));
    c11 = frn_add(c11, frn_mul(ry[k], ry[k]));
  }
  c00 = frn_div(c00, 4.0f); c01 = frn_div(c01, 4.0f); c11 = frn_div(c11, 4.0f);
  float A = frn_add(c00, 1e-6f), Bv = c01, C = frn_add(c11, 1e-6f);

  // ---- ssteqr 2x2 replica ----
  float absA = fabsf(A), absC = fabsf(C), absB = fabsf(Bv);
  float thr = frn_mul(frn_mul(sqrtf(absA), sqrtf(absC)), EPS_L);
  bool diag = (absB == 0.f) || (absB <= thr);
  if (!diag) {
    bool qr = (absC < absA);
    float b2 = frn_mul(absB, absB);
    float t = qr ? frn_add(frn_mul(frn_mul(EPS2_L, absC), absA), SAFMIN_L)
                 : frn_add(frn_mul(frn_mul(EPS2_L, absA), absC), SAFMIN_L);
    if (b2 <= t) diag = true;
  }
  float e1, e2, v00, v10, v01, v11;
  if (diag) {
    if (C < A) { e1 = C; e2 = A; v00 = 0.f; v10 = 1.f; v01 = 1.f; v11 = 0.f; }
    else       { e1 = A; e2 = C; v00 = 1.f; v10 = 0.f; v01 = 0.f; v11 = 1.f; }
  } else {
    // ---- SLAEV2 replica ----
    float sm = frn_add(A, C), df = frn_sub(A, C);
    float adf = fabsf(df), tb = frn_add(Bv, Bv), ab = fabsf(tb);
    float rt;
    if (adf > ab) {
      float r = frn_div(ab, adf);
      rt = frn_mul(adf, sqrtf(frn_add(1.0f, frn_mul(r, r))));
    } else if (adf < ab) {
      float r = frn_div(adf, ab);
      rt = frn_mul(ab, sqrtf(frn_add(1.0f, frn_mul(r, r))));
    } else {
      rt = frn_mul(ab, sqrtf(2.0f));
    }
    float acmx, acmn;
    if (absA > absC) { acmx = A; acmn = C; } else { acmx = C; acmn = A; }
    float rt1, rt2; int sgn1;
    if (sm < 0.f) {
      rt1 = frn_mul(0.5f, frn_sub(sm, rt)); sgn1 = -1;
      rt2 = frn_sub(frn_mul(frn_div(acmx, rt1), acmn), frn_mul(frn_div(Bv, rt1), Bv));
    } else if (sm > 0.f) {
      rt1 = frn_mul(0.5f, frn_add(sm, rt)); sgn1 = 1;
      rt2 = frn_sub(frn_mul(frn_div(acmx, rt1), acmn), frn_mul(frn_div(Bv, rt1), Bv));
    } else {
      rt1 = frn_mul(0.5f, rt); rt2 = frn_mul(-0.5f, rt); sgn1 = 1;
    }
    float cs, cs1, sn1; int sgn2;
    if (df >= 0.f) { cs = frn_add(df, rt); sgn2 = 1; }
    else           { cs = frn_sub(df, rt); sgn2 = -1; }
    float acs = fabsf(cs);
    if (acs > ab) {
      float ct = frn_div(-tb, cs);
      sn1 = frn_div(1.0f, sqrtf(frn_add(1.0f, frn_mul(ct, ct))));
      cs1 = frn_mul(ct, sn1);
    } else {
      if (ab == 0.f) { cs1 = 1.0f; sn1 = 0.0f; }
      else {
        float tn = frn_div(-cs, tb);
        cs1 = frn_div(1.0f, sqrtf(frn_add(1.0f, frn_mul(tn, tn))));
        sn1 = frn_mul(tn, cs1);
      }
    }
    if (sgn1 == sgn2) { float t = cs1; cs1 = -sn1; sn1 = t; }
    if (rt2 < rt1) { e1 = rt2; e2 = rt1; v00 = -sn1; v10 = cs1; v01 = cs1;  v11 = sn1; }
    else           { e1 = rt1; e2 = rt2; v00 = cs1;  v10 = sn1; v01 = -sn1; v11 = cs1; }
  }

  angle_out[p] = atan2f(v11, v01);
  float aM = sqrtf(fmaxf(e2, 1e-6f));
  float am = sqrtf(fmaxf(e1, 1e-6f));
  float den = frn_add(fmaxf(aM, am), 1e-6f);
  axes_out[2 * p]     = fmaxf(frn_div(aM, den), 0.2f);
  axes_out[2 * p + 1] = fmaxf(frn_div(am, den), 0.2f);

  // ---- fused local layer 1 ----
  float l0[5], l1v[5];
#pragma unroll
  for (int k = 0; k < 5; k++) {
    l0[k]  = frn_add(frn_mul(rx[k], v00), frn_mul(ry[k], v10));
    l1v[k] = frn_add(frn_mul(rx[k], v01), frn_mul(ry[k], v11));
  }
  size_t rowb = (size_t)p * 5;
  for (int f = 0; f < 64; ++f) {
    float wa = lw1t[f * 2], wb = lw1t[f * 2 + 1], bb = lb1[f];
#pragma unroll
    for (int k = 0; k < 5; k++) {
      float h = fmaf(l1v[k], wb, fmaf(l0[k], wa, bb));
      h1[(size_t)f * ROWS + rowb + k] = fmaxf(h, 0.f);
    }
  }
}

// ---------------------------------------------------------------------------
// Register-tiled fp32 GEMM: out[n][m] = relu(bias[n] + sum_k w[n][k]*in[k][m])
// Block tile MB x NB (MB*NB = 16384), 256 threads, micro-tile 8x8/thread,
// K staged in 16-slices in LDS (both operands), all-vector inner loop:
// per k-step 4x ds_read_b128 + 64 v_fma -> VALU-bound by design.
// Accumulation chain per output: bias first, k ascending (bit-exact vs ref).
// ---------------------------------------------------------------------------
template <int MB, int NB, int KTILES>
__global__ __launch_bounds__(256, 3) void gemm_f32(
    const float* __restrict__ in_t, const float* __restrict__ wt,
    const float* __restrict__ bias, float* __restrict__ out_t,
    int M, int Kstr) {
  constexpr int KB = 16;
  __shared__ float alds[KB * MB];
  __shared__ float wlds[KB * NB];
  int t = threadIdx.x;
  int m0 = blockIdx.x * MB;
  constexpr int TM = MB / 8;                  // 16 or 32 m-positions
  constexpr int TMS = (MB == 128) ? 4 : 5;    // log2(TM)
  int tm = t & (TM - 1);
  int tn = t >> TMS;
  float acc[8][8];
#pragma unroll
  for (int j = 0; j < 8; j++) {
    float b = bias[tn * 8 + j];
#pragma unroll
    for (int i = 0; i < 8; i++) acc[j][i] = b;
  }
  for (int kt = 0; kt < KTILES; kt++) {
    int k0 = kt * KB;
    __syncthreads();
    constexpr int APASS = (KB * MB / 4) / 256;
#pragma unroll
    for (int pp = 0; pp < APASS; pp++) {
      int e = pp * 256 + t;
      int kk = e / (MB / 4);
      int m4 = e - kk * (MB / 4);
      float4 v = *(const float4*)(in_t + (size_t)(k0 + kk) * M + m0 + m4 * 4);
      *(float4*)(alds + kk * MB + m4 * 4) = v;
    }
    constexpr int WPASS = (KB * NB / 4) / 256;
#pragma unroll
    for (int pp = 0; pp < WPASS; pp++) {
      int e = pp * 256 + t;
      int n = e >> 2;            // KB/4 = 4 k-chunks per n
      int kc = e & 3;
      float4 v = *(const float4*)(wt + (size_t)n * Kstr + k0 + kc * 4);
      wlds[(kc * 4 + 0) * NB + n] = v.x;
      wlds[(kc * 4 + 1) * NB + n] = v.y;
      wlds[(kc * 4 + 2) * NB + n] = v.z;
      wlds[(kc * 4 + 3) * NB + n] = v.w;
    }
    __syncthreads();
#pragma unroll
    for (int kk = 0; kk < KB; kk++) {
      float af[8], wf[8];
      *(float4*)(af)     = *(const float4*)(alds + kk * MB + tm * 8);
      *(float4*)(af + 4) = *(const float4*)(alds + kk * MB + tm * 8 + 4);
      *(float4*)(wf)     = *(const float4*)(wlds + kk * NB + tn * 8);
      *(float4*)(wf + 4) = *(const float4*)(wlds + kk * NB + tn * 8 + 4);
#pragma unroll
      for (int j = 0; j < 8; j++)
#pragma unroll
        for (int i = 0; i < 8; i++)
          acc[j][i] = fmaf(af[i], wf[j], acc[j][i]);
    }
  }
#pragma unroll
  for (int j = 0; j < 8; j++) {
    int n = tn * 8 + j;
    float4 o0, o1;
    o0.x = fmaxf(acc[j][0], 0.f); o0.y = fmaxf(acc[j][1], 0.f);
    o0.z = fmaxf(acc[j][2], 0.f); o0.w = fmaxf(acc[j][3], 0.f);
    o1.x = fmaxf(acc[j][4], 0.f); o1.y = fmaxf(acc[j][5], 0.f);
    o1.z = fmaxf(acc[j][6], 0.f); o1.w = fmaxf(acc[j][7], 0.f);
    float* dst = out_t + (size_t)n * M + m0 + tm * 8;
    *(float4*)(dst) = o0;
    *(float4*)(dst + 4) = o1;
  }
}

// ---------------------------------------------------------------------------
// Max over K=5 rows -> lftx rows 2..65 ; rows 0..1 = x passthrough.
// ---------------------------------------------------------------------------
__global__ __launch_bounds__(256) void maxpack(const float* __restrict__ h3,
                                               const float* __restrict__ x,
                                               float* __restrict__ lftx) {
  int idx = blockIdx.x * 256 + threadIdx.x;
  int f = idx >> 15;
  int p = idx & (PTS - 1);
  if (f < 64) {
    const float* hr = h3 + (size_t)f * ROWS + (size_t)p * 5;
    float m = fmaxf(fmaxf(fmaxf(hr[0], hr[1]), fmaxf(hr[2], hr[3])), hr[4]);
    lftx[(size_t)(f + 2) * PTS + p] = m;
  } else if (f < 66) {
    int i = f - 64;
    lftx[(size_t)i * PTS + p] = x[(size_t)p * 2 + i];
  }
}

// ---------------------------------------------------------------------------
// Transpose [256][32768] feature-major head outputs into d_out row-major.
// ---------------------------------------------------------------------------
__global__ __launch_bounds__(256) void transpose_out(const float* __restrict__ o_t, float* __restrict__ out) {
  __shared__ float tile[64][65];
  int p0 = blockIdx.x * 64;
  int j0 = blockIdx.y * 64;
  int tc = threadIdx.x & 63, tr = threadIdx.x >> 6;
#pragma unroll
  for (int rr = 0; rr < 16; rr++) {
    int j = tr + rr * 4;
    tile[j][tc] = o_t[(size_t)(j0 + j) * PTS + p0 + tc];
  }
  __syncthreads();
#pragma unroll
  for (int rr = 0; rr < 16; rr++) {
    int pl = tr + rr * 4;
    int p = p0 + pl;
    int j = j0 + tc;
    float v = tile[tc][pl];
    size_t o = (j < 128) ? ((size_t)p * 128 + j)
                         : ((size_t)4194304 + (size_t)p * 128 + (j - 128));
    out[o] = v;
  }
}

// ---------------------------------------------------------------------------
extern "C" void kernel_launch(void* const* d_in, const int* in_sizes, int n_in,
                              void* d_out, int out_size, void* d_ws, size_t ws_size,
                              hipStream_t stream) {
  const float* x   = (const float*)d_in[0];
  const float* lb1 = (const float*)d_in[2];
  const float* lb2 = (const float*)d_in[4];
  const float* lb3 = (const float*)d_in[6];
  const float* cb1 = (const float*)d_in[8];
  const float* cb2 = (const float*)d_in[10];
  const float* tb1 = (const float*)d_in[12];
  const float* tb2 = (const float*)d_in[14];

  float* out = (float*)d_out;
  float* angle_out = out + 8388608;   // after cls(4194304)+topo(4194304)
  float* axes_out  = out + 8421376;

  // Workspace layout (floats), lifetime-overlapped regions:
  //   wt   [67712]   zero-padded transposed weights
  //   R1   [10485760]  ipart (knn->merge) then h3 (l3->maxpack)
  //   R2   [10485760]  h1 (merge->l2) then a1 (c1->c2, t1->t2)
  //   R3   [20971520]  h2 (l2->l3) then outct+outtt (heads->transpose)
  //   lftx [2621440]   80 rows x PTS (rows 66..79 = pad, zero weights)
  // total ~44.6M floats = 178.5 MB (R5 proved >= 228 MB available)
  float* W = (float*)d_ws;
  float* wt   = W;
  float* R1   = W + 67712;
  float* R2   = R1 + 10485760;
  float* R3   = R2 + 10485760;
  float* lftx = R3 + 20971520;
  unsigned int* ipart = (unsigned int*)R1;
  float* h3    = R1;
  float* h1    = R2;
  float* a1    = R2;
  float* h2    = R3;
  float* outct = R3;
  float* outtt = R3 + 4194304;

  prep_w<<<7, 256, 0, stream>>>((const float*)d_in[1], (const float*)d_in[3], (const float*)d_in[5],
                                (const float*)d_in[7], (const float*)d_in[9],
                                (const float*)d_in[11], (const float*)d_in[13], wt);
  knn_scan<<<1024, 256, 0, stream>>>(x, ipart);
  merge_geom<<<128, 256, 0, stream>>>(x, ipart, wt + 0, lb1, h1, angle_out, axes_out);

  // local MLP layers 2,3 over 163840 rows
  gemm_f32<128, 128, 4><<<ROWS / 128, 256, 0, stream>>>(h1, wt + 128, lb2, h2, ROWS, 64);
  gemm_f32<256, 64, 8><<<ROWS / 256, 256, 0, stream>>>(h2, wt + 8320, lb3, h3, ROWS, 128);
  maxpack<<<(66 * PTS) / 256, 256, 0, stream>>>(h3, x, lftx);

  // heads over 32768 rows
  gemm_f32<128, 128, 5><<<PTS / 128, 256, 0, stream>>>(lftx, wt + 16512, cb1, a1, PTS, 80);
  gemm_f32<128, 128, 8><<<PTS / 128, 256, 0, stream>>>(a1, wt + 26752, cb2, outct, PTS, 128);
  gemm_f32<128, 128, 4><<<PTS / 128, 256, 0, stream>>>(lftx + 2 * PTS, wt + 43136, tb1, a1, PTS, 64);
  gemm_f32<128, 128, 8><<<PTS / 128, 256, 0, stream>>>(a1, wt + 51328, tb2, outtt, PTS, 128);

  transpose_out<<<dim3(512, 4), 256, 0, stream>>>(outct, out);
}

// Round 8
// 399.349 us; speedup vs baseline: 2.0174x; 1.0356x over previous
//
#include <hip/hip_runtime.h>
#include <math.h>

#pragma clang fp contract(off)

#define NPTS 4096
#define PTS  32768
#define ROWS 163840   // PTS * 5
#define QN   8        // candidate slices per batch
#define QLEN 512      // NPTS / QN
#define SLOTS 8       // packed top-k slots per slice (and global survivors)

// LAPACK single-precision machine constants (gfortran/IEEE):
#define EPS_L   5.9604644775390625e-8f    // 2^-24  SLAMCH('E')
#define EPS2_L  3.5527136788005009e-15f   // 2^-48
#define SAFMIN_L 1.1754943508222875e-38f  // 2^-126

// Round-to-nearest, non-contractible f32 ops (file pragma disables fusion).
__device__ __forceinline__ float frn_mul(float a, float b) { float r = a * b; return r; }
__device__ __forceinline__ float frn_add(float a, float b) { float r = a + b; return r; }
__device__ __forceinline__ float frn_sub(float a, float b) { float r = a - b; return r; }
__device__ __forceinline__ float frn_div(float a, float b) { float r = a / b; return r; }

__device__ __forceinline__ float ref_sq(float x0, float x1) {
  return frn_add(frn_mul(x0, x0), frn_mul(x1, x1));
}
// dist_sq[n,m] = fl( fl(sq_n + sq_m) - 2*dot ), dot = fma(ny*my, fl(nx*mx)).
__device__ __forceinline__ float ref_key(float nx, float ny, float sqn,
                                         float mx, float my, float sqm) {
  float dot = fmaf(ny, my, frn_mul(nx, mx));
  float s = frn_add(sqn, sqm);
  return fmaf(-2.0f, dot, s);
}

// ---------------------------------------------------------------------------
// Weight transpose prep, zero-padded K stride: wt[j*Kp + i] = (i<K)? w[i*N+j]:0
// ---------------------------------------------------------------------------
__global__ __launch_bounds__(256) void prep_w(
    const float* __restrict__ lw1, const float* __restrict__ lw2, const float* __restrict__ lw3,
    const float* __restrict__ cw1, const float* __restrict__ cw2,
    const float* __restrict__ tw1, const float* __restrict__ tw2,
    float* __restrict__ wt) {
  const int Ks[7]   = {2, 64, 128, 66, 128, 64, 128};
  const int Kp[7]   = {2, 64, 128, 80, 128, 64, 128};
  const int Ns[7]   = {64, 128, 64, 128, 128, 128, 128};
  const int offs[7] = {0, 128, 8320, 16512, 26752, 43136, 51328};
  const float* srcs[7] = {lw1, lw2, lw3, cw1, cw2, tw1, tw2};
  int b = blockIdx.x;
  const float* src = srcs[b];
  float* dst = wt + offs[b];
  int K = Ks[b], KP = Kp[b], N = Ns[b];
  for (int e = threadIdx.x; e < KP * N; e += 256) {
    int j = e / KP, i = e - j * KP;
    dst[e] = (i < K) ? src[i * N + j] : 0.0f;
  }
}

// ---------------------------------------------------------------------------
// kNN scan: 1024 blocks = 128 point-groups x 8 candidate-slices.
// Threshold-filtered top-8: each candidate costs ~1 cmp + buffered append;
// the 16-op sort network runs only on survivors (lazy flush when any lane's
// 16-entry LDS buffer fills). Packed value = (bits(dist)&0xFFFFF000)|idx
// (direct-form dist >= 0 is u32-monotone). Monotone threshold T guarantees
// no true top-8 element is dropped. Exact ref-key re-rank happens in merge.
// ---------------------------------------------------------------------------
__global__ __launch_bounds__(256) void knn_scan(const float* __restrict__ x,
                                                unsigned int* __restrict__ ipart) {
  __shared__ float2 cand[QLEN];            // 4 KB
  __shared__ unsigned int sbuf[17 * 256];  // 17 KB survivor buffer (row 16 = trash)
  int bx = blockIdx.x;
  int q = bx & (QN - 1);
  int pg = bx >> 3;
  int batch = pg >> 4;
  const float* xb = x + (size_t)batch * NPTS * 2;
  int c0 = q * QLEN;
  for (int i = threadIdx.x; i < QLEN; i += 256)
    cand[i] = ((const float2*)xb)[c0 + i];
  __syncthreads();
  int t = threadIdx.x;
  int p = pg * 256 + t;
  float2 me = ((const float2*)x)[p];
  unsigned int d[SLOTS];
#pragma unroll
  for (int s = 0; s < SLOTS; s++) d[s] = 0xFFFFFFFFu;
  unsigned int T = 0xFFFFFFFFu;
  unsigned int cnt = 0;
  for (int m = 0; m < QLEN; m++) {
    float2 c = cand[m];
    float dx = me.x - c.x, dy = me.y - c.y;
    float dist = fmaf(dy, dy, dx * dx);
    unsigned int v = (__float_as_uint(dist) & 0xFFFFF000u) | (unsigned int)(c0 + m);
    bool pass = v < T;
    unsigned int slot = pass ? cnt : 16u;
    sbuf[slot * 256 + t] = v;
    cnt += pass ? 1u : 0u;
    if (__any(cnt >= 16u)) {
#pragma unroll
      for (int j = 0; j < 16; j++) {
        unsigned int u = ((unsigned)j < cnt) ? sbuf[j * 256 + t] : 0xFFFFFFFFu;
#pragma unroll
        for (int s = 0; s < SLOTS; s++) {
          unsigned int lo = min(u, d[s]);
          unsigned int hi = max(u, d[s]);
          d[s] = lo; u = hi;
        }
      }
      cnt = 0;
      T = d[SLOTS - 1];
    }
  }
  // final flush of residual buffer entries
#pragma unroll
  for (int j = 0; j < 16; j++) {
    unsigned int u = ((unsigned)j < cnt) ? sbuf[j * 256 + t] : 0xFFFFFFFFu;
#pragma unroll
    for (int s = 0; s < SLOTS; s++) {
      unsigned int lo = min(u, d[s]);
      unsigned int hi = max(u, d[s]);
      d[s] = lo; u = hi;
    }
  }
#pragma unroll
  for (int s = 0; s < SLOTS; s++)
    ipart[((size_t)(q * SLOTS + s)) * PTS + p] = d[s];
}

// ---------------------------------------------------------------------------
// Merge + geometry + FUSED local layer 1 (K=2 -> 64, ReLU), h1 feature-major.
// ---------------------------------------------------------------------------
__global__ __launch_bounds__(256) void merge_geom(const float* __restrict__ x,
    const unsigned int* __restrict__ ipart,
    const float* __restrict__ lw1t, const float* __restrict__ lb1,
    float* __restrict__ h1,
    float* __restrict__ angle_out, float* __restrict__ axes_out) {
  int p = blockIdx.x * 256 + threadIdx.x;
  int batch = p >> 12;
  const float2* xb = (const float2*)(x + (size_t)batch * NPTS * 2);
  float2 me = ((const float2*)x)[p];
  float sqn = ref_sq(me.x, me.y);

  unsigned int g[SLOTS];
#pragma unroll
  for (int s = 0; s < SLOTS; s++) g[s] = 0xFFFFFFFFu;
  for (int qs = 0; qs < QN * SLOTS; qs++) {
    unsigned int v = ipart[(size_t)qs * PTS + p];
#pragma unroll
    for (int s = 0; s < SLOTS; s++) {
      unsigned int lo = min(v, g[s]);
      unsigned int hi = max(v, g[s]);
      g[s] = lo; v = hi;
    }
  }
  float dk[5]; int id[5];
#pragma unroll
  for (int s = 0; s < 5; s++) { dk[s] = 3.0e38f; id[s] = 0x7fffffff; }
#pragma unroll
  for (int s8 = 0; s8 < SLOTS; s8++) {
    int ci = (int)(g[s8] & 0xFFFu);
    float2 c = xb[ci];
    float key = ref_key(me.x, me.y, sqn, c.x, c.y, ref_sq(c.x, c.y));
    float v = key; int vi = ci;
#pragma unroll
    for (int s = 0; s < 5; s++) {
      bool lt = (v < dk[s]) || (v == dk[s] && vi < id[s]);
      float tv = dk[s]; int ti = id[s];
      if (lt) { dk[s] = v; id[s] = vi; v = tv; vi = ti; }
    }
  }
  float rx[5], ry[5];
  float sx = 0.f, sy = 0.f;
#pragma unroll
  for (int k = 0; k < 5; k++) {
    float2 nb = xb[id[k]];
    rx[k] = frn_sub(nb.x, me.x); ry[k] = frn_sub(nb.y, me.y);
    sx = frn_add(sx, rx[k]); sy = frn_add(sy, ry[k]);
  }
  float mx = frn_div(sx, 5.0f), my = frn_div(sy, 5.0f);
  float c00 = 0.f, c01 = 0.f, c11 = 0.f;
#pragma unroll
  for (int k = 0; k < 5; k++) {
    rx[k] = frn_sub(rx[k], mx); ry[k] = frn_sub(ry[k], my);
    c00 = frn_add(c00, frn_mul(rx[k], rx[k]));
    c01 = frn_add(c01, frn_mul(rx[k], ry[k]));
    c11 = frn_add(c11, frn_mul(ry[k], ry[k]));
  }
  c00 = frn_div(c00, 4.0f); c01 = frn_div(c01, 4.0f); c11 = frn_div(c11, 4.0f);
  float A = frn_add(c00, 1e-6f), Bv = c01, C = frn_add(c11, 1e-6f);

  // ---- ssteqr 2x2 replica ----
  float absA = fabsf(A), absC = fabsf(C), absB = fabsf(Bv);
  float thr = frn_mul(frn_mul(sqrtf(absA), sqrtf(absC)), EPS_L);
  bool diag = (absB == 0.f) || (absB <= thr);
  if (!diag) {
    bool qr = (absC < absA);
    float b2 = frn_mul(absB, absB);
    float t = qr ? frn_add(frn_mul(frn_mul(EPS2_L, absC), absA), SAFMIN_L)
                 : frn_add(frn_mul(frn_mul(EPS2_L, absA), absC), SAFMIN_L);
    if (b2 <= t) diag = true;
  }
  float e1, e2, v00, v10, v01, v11;
  if (diag) {
    if (C < A) { e1 = C; e2 = A; v00 = 0.f; v10 = 1.f; v01 = 1.f; v11 = 0.f; }
    else       { e1 = A; e2 = C; v00 = 1.f; v10 = 0.f; v01 = 0.f; v11 = 1.f; }
  } else {
    // ---- SLAEV2 replica ----
    float sm = frn_add(A, C), df = frn_sub(A, C);
    float adf = fabsf(df), tb = frn_add(Bv, Bv), ab = fabsf(tb);
    float rt;
    if (adf > ab) {
      float r = frn_div(ab, adf);
      rt = frn_mul(adf, sqrtf(frn_add(1.0f, frn_mul(r, r))));
    } else if (adf < ab) {
      float r = frn_div(adf, ab);
      rt = frn_mul(ab, sqrtf(frn_add(1.0f, frn_mul(r, r))));
    } else {
      rt = frn_mul(ab, sqrtf(2.0f));
    }
    float acmx, acmn;
    if (absA > absC) { acmx = A; acmn = C; } else { acmx = C; acmn = A; }
    float rt1, rt2; int sgn1;
    if (sm < 0.f) {
      rt1 = frn_mul(0.5f, frn_sub(sm, rt)); sgn1 = -1;
      rt2 = frn_sub(frn_mul(frn_div(acmx, rt1), acmn), frn_mul(frn_div(Bv, rt1), Bv));
    } else if (sm > 0.f) {
      rt1 = frn_mul(0.5f, frn_add(sm, rt)); sgn1 = 1;
      rt2 = frn_sub(frn_mul(frn_div(acmx, rt1), acmn), frn_mul(frn_div(Bv, rt1), Bv));
    } else {
      rt1 = frn_mul(0.5f, rt); rt2 = frn_mul(-0.5f, rt); sgn1 = 1;
    }
    float cs, cs1, sn1; int sgn2;
    if (df >= 0.f) { cs = frn_add(df, rt); sgn2 = 1; }
    else           { cs = frn_sub(df, rt); sgn2 = -1; }
    float acs = fabsf(cs);
    if (acs > ab) {
      float ct = frn_div(-tb, cs);
      sn1 = frn_div(1.0f, sqrtf(frn_add(1.0f, frn_mul(ct, ct))));
      cs1 = frn_mul(ct, sn1);
    } else {
      if (ab == 0.f) { cs1 = 1.0f; sn1 = 0.0f; }
      else {
        float tn = frn_div(-cs, tb);
        cs1 = frn_div(1.0f, sqrtf(frn_add(1.0f, frn_mul(tn, tn))));
        sn1 = frn_mul(tn, cs1);
      }
    }
    if (sgn1 == sgn2) { float t = cs1; cs1 = -sn1; sn1 = t; }
    if (rt2 < rt1) { e1 = rt2; e2 = rt1; v00 = -sn1; v10 = cs1; v01 = cs1;  v11 = sn1; }
    else           { e1 = rt1; e2 = rt2; v00 = cs1;  v10 = sn1; v01 = -sn1; v11 = cs1; }
  }

  angle_out[p] = atan2f(v11, v01);
  float aM = sqrtf(fmaxf(e2, 1e-6f));
  float am = sqrtf(fmaxf(e1, 1e-6f));
  float den = frn_add(fmaxf(aM, am), 1e-6f);
  axes_out[2 * p]     = fmaxf(frn_div(aM, den), 0.2f);
  axes_out[2 * p + 1] = fmaxf(frn_div(am, den), 0.2f);

  // ---- fused local layer 1 ----
  float l0[5], l1v[5];
#pragma unroll
  for (int k = 0; k < 5; k++) {
    l0[k]  = frn_add(frn_mul(rx[k], v00), frn_mul(ry[k], v10));
    l1v[k] = frn_add(frn_mul(rx[k], v01), frn_mul(ry[k], v11));
  }
  size_t rowb = (size_t)p * 5;
  for (int f = 0; f < 64; ++f) {
    float wa = lw1t[f * 2], wb = lw1t[f * 2 + 1], bb = lb1[f];
#pragma unroll
    for (int k = 0; k < 5; k++) {
      float h = fmaf(l1v[k], wb, fmaf(l0[k], wa, bb));
      h1[(size_t)f * ROWS + rowb + k] = fmaxf(h, 0.f);
    }
  }
}

// ---------------------------------------------------------------------------
// Register-tiled fp32 GEMM: out[n][m] = relu(bias[n] + sum_k w[n][k]*in[k][m])
// ---------------------------------------------------------------------------
template <int MB, int NB, int KTILES>
__global__ __launch_bounds__(256, 3) void gemm_f32(
    const float* __restrict__ in_t, const float* __restrict__ wt,
    const float* __restrict__ bias, float* __restrict__ out_t,
    int M, int Kstr) {
  constexpr int KB = 16;
  __shared__ float alds[KB * MB];
  __shared__ float wlds[KB * NB];
  int t = threadIdx.x;
  int m0 = blockIdx.x * MB;
  constexpr int TM = MB / 8;
  constexpr int TMS = (MB == 128) ? 4 : 5;
  int tm = t & (TM - 1);
  int tn = t >> TMS;
  float acc[8][8];
#pragma unroll
  for (int j = 0; j < 8; j++) {
    float b = bias[tn * 8 + j];
#pragma unroll
    for (int i = 0; i < 8; i++) acc[j][i] = b;
  }
  for (int kt = 0; kt < KTILES; kt++) {
    int k0 = kt * KB;
    __syncthreads();
    constexpr int APASS = (KB * MB / 4) / 256;
#pragma unroll
    for (int pp = 0; pp < APASS; pp++) {
      int e = pp * 256 + t;
      int kk = e / (MB / 4);
      int m4 = e - kk * (MB / 4);
      float4 v = *(const float4*)(in_t + (size_t)(k0 + kk) * M + m0 + m4 * 4);
      *(float4*)(alds + kk * MB + m4 * 4) = v;
    }
    constexpr int WPASS = (KB * NB / 4) / 256;
#pragma unroll
    for (int pp = 0; pp < WPASS; pp++) {
      int e = pp * 256 + t;
      int n = e >> 2;
      int kc = e & 3;
      float4 v = *(const float4*)(wt + (size_t)n * Kstr + k0 + kc * 4);
      wlds[(kc * 4 + 0) * NB + n] = v.x;
      wlds[(kc * 4 + 1) * NB + n] = v.y;
      wlds[(kc * 4 + 2) * NB + n] = v.z;
      wlds[(kc * 4 + 3) * NB + n] = v.w;
    }
    __syncthreads();
#pragma unroll
    for (int kk = 0; kk < KB; kk++) {
      float af[8], wf[8];
      *(float4*)(af)     = *(const float4*)(alds + kk * MB + tm * 8);
      *(float4*)(af + 4) = *(const float4*)(alds + kk * MB + tm * 8 + 4);
      *(float4*)(wf)     = *(const float4*)(wlds + kk * NB + tn * 8);
      *(float4*)(wf + 4) = *(const float4*)(wlds + kk * NB + tn * 8 + 4);
#pragma unroll
      for (int j = 0; j < 8; j++)
#pragma unroll
        for (int i = 0; i < 8; i++)
          acc[j][i] = fmaf(af[i], wf[j], acc[j][i]);
    }
  }
#pragma unroll
  for (int j = 0; j < 8; j++) {
    int n = tn * 8 + j;
    float4 o0, o1;
    o0.x = fmaxf(acc[j][0], 0.f); o0.y = fmaxf(acc[j][1], 0.f);
    o0.z = fmaxf(acc[j][2], 0.f); o0.w = fmaxf(acc[j][3], 0.f);
    o1.x = fmaxf(acc[j][4], 0.f); o1.y = fmaxf(acc[j][5], 0.f);
    o1.z = fmaxf(acc[j][6], 0.f); o1.w = fmaxf(acc[j][7], 0.f);
    float* dst = out_t + (size_t)n * M + m0 + tm * 8;
    *(float4*)(dst) = o0;
    *(float4*)(dst + 4) = o1;
  }
}

// ---------------------------------------------------------------------------
// Max over K=5 rows -> lftx rows 2..65 ; rows 0..1 = x passthrough.
// ---------------------------------------------------------------------------
__global__ __launch_bounds__(256) void maxpack(const float* __restrict__ h3,
                                               const float* __restrict__ x,
                                               float* __restrict__ lftx) {
  int idx = blockIdx.x * 256 + threadIdx.x;
  int f = idx >> 15;
  int p = idx & (PTS - 1);
  if (f < 64) {
    const float* hr = h3 + (size_t)f * ROWS + (size_t)p * 5;
    float m = fmaxf(fmaxf(fmaxf(hr[0], hr[1]), fmaxf(hr[2], hr[3])), hr[4]);
    lftx[(size_t)(f + 2) * PTS + p] = m;
  } else if (f < 66) {
    int i = f - 64;
    lftx[(size_t)i * PTS + p] = x[(size_t)p * 2 + i];
  }
}

// ---------------------------------------------------------------------------
// Transpose [256][32768] feature-major head outputs into d_out row-major.
// ---------------------------------------------------------------------------
__global__ __launch_bounds__(256) void transpose_out(const float* __restrict__ o_t, float* __restrict__ out) {
  __shared__ float tile[64][65];
  int p0 = blockIdx.x * 64;
  int j0 = blockIdx.y * 64;
  int tc = threadIdx.x & 63, tr = threadIdx.x >> 6;
#pragma unroll
  for (int rr = 0; rr < 16; rr++) {
    int j = tr + rr * 4;
    tile[j][tc] = o_t[(size_t)(j0 + j) * PTS + p0 + tc];
  }
  __syncthreads();
#pragma unroll
  for (int rr = 0; rr < 16; rr++) {
    int pl = tr + rr * 4;
    int p = p0 + pl;
    int j = j0 + tc;
    float v = tile[tc][pl];
    size_t o = (j < 128) ? ((size_t)p * 128 + j)
                         : ((size_t)4194304 + (size_t)p * 128 + (j - 128));
    out[o] = v;
  }
}

// ---------------------------------------------------------------------------
extern "C" void kernel_launch(void* const* d_in, const int* in_sizes, int n_in,
                              void* d_out, int out_size, void* d_ws, size_t ws_size,
                              hipStream_t stream) {
  const float* x   = (const float*)d_in[0];
  const float* lb1 = (const float*)d_in[2];
  const float* lb2 = (const float*)d_in[4];
  const float* lb3 = (const float*)d_in[6];
  const float* cb1 = (const float*)d_in[8];
  const float* cb2 = (const float*)d_in[10];
  const float* tb1 = (const float*)d_in[12];
  const float* tb2 = (const float*)d_in[14];

  float* out = (float*)d_out;
  float* angle_out = out + 8388608;
  float* axes_out  = out + 8421376;

  float* W = (float*)d_ws;
  float* wt   = W;
  float* R1   = W + 67712;
  float* R2   = R1 + 10485760;
  float* R3   = R2 + 10485760;
  float* lftx = R3 + 20971520;
  unsigned int* ipart = (unsigned int*)R1;
  float* h3    = R1;
  float* h1    = R2;
  float* a1    = R2;
  float* h2    = R3;
  float* outct = R3;
  float* outtt = R3 + 4194304;

  prep_w<<<7, 256, 0, stream>>>((const float*)d_in[1], (const float*)d_in[3], (const float*)d_in[5],
                                (const float*)d_in[7], (const float*)d_in[9],
                                (const float*)d_in[11], (const float*)d_in[13], wt);
  knn_scan<<<1024, 256, 0, stream>>>(x, ipart);
  merge_geom<<<128, 256, 0, stream>>>(x, ipart, wt + 0, lb1, h1, angle_out, axes_out);

  gemm_f32<128, 128, 4><<<ROWS / 128, 256, 0, stream>>>(h1, wt + 128, lb2, h2, ROWS, 64);
  gemm_f32<256, 64, 8><<<ROWS / 256, 256, 0, stream>>>(h2, wt + 8320, lb3, h3, ROWS, 128);
  maxpack<<<(66 * PTS) / 256, 256, 0, stream>>>(h3, x, lftx);

  gemm_f32<128, 128, 5><<<PTS / 128, 256, 0, stream>>>(lftx, wt + 16512, cb1, a1, PTS, 80);
  gemm_f32<128, 128, 8><<<PTS / 128, 256, 0, stream>>>(a1, wt + 26752, cb2, outct, PTS, 128);
  gemm_f32<128, 128, 4><<<PTS / 128, 256, 0, stream>>>(lftx + 2 * PTS, wt + 43136, tb1, a1, PTS, 64);
  gemm_f32<128, 128, 8><<<PTS / 128, 256, 0, stream>>>(a1, wt + 51328, tb2, outtt, PTS, 128);

  transpose_out<<<dim3(512, 4), 256, 0, stream>>>(outct, out);
}

// Round 10
// 386.350 us; speedup vs baseline: 2.0853x; 1.0336x over previous
//
#include <hip/hip_runtime.h>
#include <math.h>

#pragma clang fp contract(off)

#define NPTS 4096
#define PTS  32768
#define ROWS 163840   // PTS * 5
#define QN   16       // candidate slices per batch
#define QLEN 256      // NPTS / QN
#define SLOTS 8       // packed top-k slots per slice (and global survivors)

// LAPACK single-precision machine constants (gfortran/IEEE):
#define EPS_L   5.9604644775390625e-8f    // 2^-24  SLAMCH('E')
#define EPS2_L  3.5527136788005009e-15f   // 2^-48
#define SAFMIN_L 1.1754943508222875e-38f  // 2^-126

// Round-to-nearest, non-contractible f32 ops (file pragma disables fusion).
__device__ __forceinline__ float frn_mul(float a, float b) { float r = a * b; return r; }
__device__ __forceinline__ float frn_add(float a, float b) { float r = a + b; return r; }
__device__ __forceinline__ float frn_sub(float a, float b) { float r = a - b; return r; }
__device__ __forceinline__ float frn_div(float a, float b) { float r = a / b; return r; }

__device__ __forceinline__ float ref_sq(float x0, float x1) {
  return frn_add(frn_mul(x0, x0), frn_mul(x1, x1));
}
// dist_sq[n,m] = fl( fl(sq_n + sq_m) - 2*dot ), dot = fma(ny*my, fl(nx*mx)).
__device__ __forceinline__ float ref_key(float nx, float ny, float sqn,
                                         float mx, float my, float sqm) {
  float dot = fmaf(ny, my, frn_mul(nx, mx));
  float s = frn_add(sqn, sqm);
  return fmaf(-2.0f, dot, s);
}

// ---------------------------------------------------------------------------
// Weight transpose prep, zero-padded K stride: wt[j*Kp + i] = (i<K)? w[i*N+j]:0
// ---------------------------------------------------------------------------
__global__ __launch_bounds__(256) void prep_w(
    const float* __restrict__ lw1, const float* __restrict__ lw2, const float* __restrict__ lw3,
    const float* __restrict__ cw1, const float* __restrict__ cw2,
    const float* __restrict__ tw1, const float* __restrict__ tw2,
    float* __restrict__ wt) {
  const int Ks[7]   = {2, 64, 128, 66, 128, 64, 128};
  const int Kp[7]   = {2, 64, 128, 80, 128, 64, 128};
  const int Ns[7]   = {64, 128, 64, 128, 128, 128, 128};
  const int offs[7] = {0, 128, 8320, 16512, 26752, 43136, 51328};
  const float* srcs[7] = {lw1, lw2, lw3, cw1, cw2, tw1, tw2};
  int b = blockIdx.x;
  const float* src = srcs[b];
  float* dst = wt + offs[b];
  int K = Ks[b], KP = Kp[b], N = Ns[b];
  for (int e = threadIdx.x; e < KP * N; e += 256) {
    int j = e / KP, i = e - j * KP;
    dst[e] = (i < K) ? src[i * N + j] : 0.0f;
  }
}

// ---------------------------------------------------------------------------
// kNN scan: 2048 blocks = 128 point-groups x 16 candidate-slices (8/CU,
// 19 KB LDS -> full occupancy ceiling). Threshold-filtered top-8, unroll-2:
// candidates cost ~1 cmp + branchless buffered append; the sort network runs
// only on survivors (lazy flush when any lane's buffer reaches 15+).
// Packed value = (bits(dist)&0xFFFFF000)|idx (direct dist >= 0 u32-monotone).
// Monotone threshold T => no true top-8 element dropped; exact ref-key
// re-rank happens in merge_geom.
// ---------------------------------------------------------------------------
__global__ __launch_bounds__(256) void knn_scan(const float* __restrict__ x,
                                                unsigned int* __restrict__ ipart) {
  __shared__ float2 cand[QLEN];            // 2 KB
  __shared__ unsigned int sbuf[17 * 256];  // 17 KB survivor buffer (row 16 = trash)
  int bx = blockIdx.x;
  int q = bx & (QN - 1);
  int pg = bx >> 4;
  int batch = pg >> 4;
  const float* xb = x + (size_t)batch * NPTS * 2;
  int c0 = q * QLEN;
  for (int i = threadIdx.x; i < QLEN; i += 256)
    cand[i] = ((const float2*)xb)[c0 + i];
  __syncthreads();
  int t = threadIdx.x;
  int p = pg * 256 + t;
  float2 me = ((const float2*)x)[p];
  unsigned int d[SLOTS];
#pragma unroll
  for (int s = 0; s < SLOTS; s++) d[s] = 0xFFFFFFFFu;
  unsigned int T = 0xFFFFFFFFu;
  unsigned int cnt = 0;
  for (int mm = 0; mm < QLEN / 2; mm++) {
    float4 cc = ((const float4*)cand)[mm];
    unsigned int idx0 = (unsigned int)(c0 + 2 * mm);
    // candidate 0
    {
      float dx = me.x - cc.x, dy = me.y - cc.y;
      float dist = fmaf(dy, dy, dx * dx);
      unsigned int v = (__float_as_uint(dist) & 0xFFFFF000u) | idx0;
      bool pass = v < T;
      sbuf[(pass ? cnt : 16u) * 256 + t] = v;
      cnt += pass ? 1u : 0u;
    }
    // candidate 1
    {
      float dx = me.x - cc.z, dy = me.y - cc.w;
      float dist = fmaf(dy, dy, dx * dx);
      unsigned int v = (__float_as_uint(dist) & 0xFFFFF000u) | (idx0 + 1u);
      bool pass = v < T;
      sbuf[(pass ? cnt : 16u) * 256 + t] = v;
      cnt += pass ? 1u : 0u;
    }
    if (__any((int)(cnt >= 15u))) {
#pragma unroll
      for (int j = 0; j < 16; j++) {
        unsigned int u = ((unsigned)j < cnt) ? sbuf[j * 256 + t] : 0xFFFFFFFFu;
#pragma unroll
        for (int s = 0; s < SLOTS; s++) {
          unsigned int lo = min(u, d[s]);
          unsigned int hi = max(u, d[s]);
          d[s] = lo; u = hi;
        }
      }
      cnt = 0;
      T = d[SLOTS - 1];
    }
  }
  // final flush of residual buffer entries
#pragma unroll
  for (int j = 0; j < 16; j++) {
    unsigned int u = ((unsigned)j < cnt) ? sbuf[j * 256 + t] : 0xFFFFFFFFu;
#pragma unroll
    for (int s = 0; s < SLOTS; s++) {
      unsigned int lo = min(u, d[s]);
      unsigned int hi = max(u, d[s]);
      d[s] = lo; u = hi;
    }
  }
#pragma unroll
  for (int s = 0; s < SLOTS; s++)
    ipart[((size_t)(q * SLOTS + s)) * PTS + p] = d[s];
}

// ---------------------------------------------------------------------------
// Merge + geometry. Gathers 128 packed survivors -> packed top-8 -> exact
// (f32 ref key, idx) lex re-rank -> reference top-5 -> covariance ->
// ssteqr/SLAEV2 replica -> angle/axes + interleaved lcc (float2).
// 256 blocks x 128 threads (full GPU; layer-1 de-fused to dense1).
// ---------------------------------------------------------------------------
__global__ __launch_bounds__(128) void merge_geom(const float* __restrict__ x,
    const unsigned int* __restrict__ ipart,
    float2* __restrict__ lcct2,
    float* __restrict__ angle_out, float2* __restrict__ axes_out) {
  int p = blockIdx.x * 128 + threadIdx.x;
  int batch = p >> 12;
  const float2* xb = (const float2*)(x + (size_t)batch * NPTS * 2);
  float2 me = ((const float2*)x)[p];
  float sqn = ref_sq(me.x, me.y);

  unsigned int g[SLOTS];
#pragma unroll
  for (int s = 0; s < SLOTS; s++) g[s] = 0xFFFFFFFFu;
  for (int qs = 0; qs < QN * SLOTS; qs++) {
    unsigned int v = ipart[(size_t)qs * PTS + p];
#pragma unroll
    for (int s = 0; s < SLOTS; s++) {
      unsigned int lo = min(v, g[s]);
      unsigned int hi = max(v, g[s]);
      g[s] = lo; v = hi;
    }
  }
  float dk[5]; int id[5];
#pragma unroll
  for (int s = 0; s < 5; s++) { dk[s] = 3.0e38f; id[s] = 0x7fffffff; }
#pragma unroll
  for (int s8 = 0; s8 < SLOTS; s8++) {
    int ci = (int)(g[s8] & 0xFFFu);
    float2 c = xb[ci];
    float key = ref_key(me.x, me.y, sqn, c.x, c.y, ref_sq(c.x, c.y));
    float v = key; int vi = ci;
#pragma unroll
    for (int s = 0; s < 5; s++) {
      bool lt = (v < dk[s]) || (v == dk[s] && vi < id[s]);
      float tv = dk[s]; int ti = id[s];
      if (lt) { dk[s] = v; id[s] = vi; v = tv; vi = ti; }
    }
  }
  float rx[5], ry[5];
  float sx = 0.f, sy = 0.f;
#pragma unroll
  for (int k = 0; k < 5; k++) {
    float2 nb = xb[id[k]];
    rx[k] = frn_sub(nb.x, me.x); ry[k] = frn_sub(nb.y, me.y);
    sx = frn_add(sx, rx[k]); sy = frn_add(sy, ry[k]);
  }
  float mx = frn_div(sx, 5.0f), my = frn_div(sy, 5.0f);
  float c00 = 0.f, c01 = 0.f, c11 = 0.f;
#pragma unroll
  for (int k = 0; k < 5; k++) {
    rx[k] = frn_sub(rx[k], mx); ry[k] = frn_sub(ry[k], my);
    c00 = frn_add(c00, frn_mul(rx[k], rx[k]));
    c01 = frn_add(c01, frn_mul(rx[k], ry[k]));
    c11 = frn_add(c11, frn_mul(ry[k], ry[k]));
  }
  c00 = frn_div(c00, 4.0f); c01 = frn_div(c01, 4.0f); c11 = frn_div(c11, 4.0f);
  float A = frn_add(c00, 1e-6f), Bv = c01, C = frn_add(c11, 1e-6f);

  // ---- ssteqr 2x2 replica ----
  float absA = fabsf(A), absC = fabsf(C), absB = fabsf(Bv);
  float thr = frn_mul(frn_mul(sqrtf(absA), sqrtf(absC)), EPS_L);
  bool diag = (absB == 0.f) || (absB <= thr);
  if (!diag) {
    bool qr = (absC < absA);
    float b2 = frn_mul(absB, absB);
    float t = qr ? frn_add(frn_mul(frn_mul(EPS2_L, absC), absA), SAFMIN_L)
                 : frn_add(frn_mul(frn_mul(EPS2_L, absA), absC), SAFMIN_L);
    if (b2 <= t) diag = true;
  }
  float e1, e2, v00, v10, v01, v11;
  if (diag) {
    if (C < A) { e1 = C; e2 = A; v00 = 0.f; v10 = 1.f; v01 = 1.f; v11 = 0.f; }
    else       { e1 = A; e2 = C; v00 = 1.f; v10 = 0.f; v01 = 0.f; v11 = 1.f; }
  } else {
    // ---- SLAEV2 replica ----
    float sm = frn_add(A, C), df = frn_sub(A, C);
    float adf = fabsf(df), tb = frn_add(Bv, Bv), ab = fabsf(tb);
    float rt;
    if (adf > ab) {
      float r = frn_div(ab, adf);
      rt = frn_mul(adf, sqrtf(frn_add(1.0f, frn_mul(r, r))));
    } else if (adf < ab) {
      float r = frn_div(adf, ab);
      rt = frn_mul(ab, sqrtf(frn_add(1.0f, frn_mul(r, r))));
    } else {
      rt = frn_mul(ab, sqrtf(2.0f));
    }
    float acmx, acmn;
    if (absA > absC) { acmx = A; acmn = C; } else { acmx = C; acmn = A; }
    float rt1, rt2; int sgn1;
    if (sm < 0.f) {
      rt1 = frn_mul(0.5f, frn_sub(sm, rt)); sgn1 = -1;
      rt2 = frn_sub(frn_mul(frn_div(acmx, rt1), acmn), frn_mul(frn_div(Bv, rt1), Bv));
    } else if (sm > 0.f) {
      rt1 = frn_mul(0.5f, frn_add(sm, rt)); sgn1 = 1;
      rt2 = frn_sub(frn_mul(frn_div(acmx, rt1), acmn), frn_mul(frn_div(Bv, rt1), Bv));
    } else {
      rt1 = frn_mul(0.5f, rt); rt2 = frn_mul(-0.5f, rt); sgn1 = 1;
    }
    float cs, cs1, sn1; int sgn2;
    if (df >= 0.f) { cs = frn_add(df, rt); sgn2 = 1; }
    else           { cs = frn_sub(df, rt); sgn2 = -1; }
    float acs = fabsf(cs);
    if (acs > ab) {
      float ct = frn_div(-tb, cs);
      sn1 = frn_div(1.0f, sqrtf(frn_add(1.0f, frn_mul(ct, ct))));
      cs1 = frn_mul(ct, sn1);
    } else {
      if (ab == 0.f) { cs1 = 1.0f; sn1 = 0.0f; }
      else {
        float tn = frn_div(-cs, tb);
        cs1 = frn_div(1.0f, sqrtf(frn_add(1.0f, frn_mul(tn, tn))));
        sn1 = frn_mul(tn, cs1);
      }
    }
    if (sgn1 == sgn2) { float t = cs1; cs1 = -sn1; sn1 = t; }
    if (rt2 < rt1) { e1 = rt2; e2 = rt1; v00 = -sn1; v10 = cs1; v01 = cs1;  v11 = sn1; }
    else           { e1 = rt1; e2 = rt2; v00 = cs1;  v10 = sn1; v01 = -sn1; v11 = cs1; }
  }

  angle_out[p] = atan2f(v11, v01);
  float aM = sqrtf(fmaxf(e2, 1e-6f));
  float am = sqrtf(fmaxf(e1, 1e-6f));
  float den = frn_add(fmaxf(aM, am), 1e-6f);
  axes_out[p] = make_float2(fmaxf(frn_div(aM, den), 0.2f),
                            fmaxf(frn_div(am, den), 0.2f));

  size_t rowb = (size_t)p * 5;
#pragma unroll
  for (int k = 0; k < 5; k++) {
    float l0 = frn_add(frn_mul(rx[k], v00), frn_mul(ry[k], v10));
    float l1 = frn_add(frn_mul(rx[k], v01), frn_mul(ry[k], v11));
    lcct2[rowb + k] = make_float2(l0, l1);
  }
}

// ---------------------------------------------------------------------------
// Local layer 1: h1[f][r] = relu(l0*wa[f] + l1*wb[f] + b[f]), K=2.
// Thread-per-row, weights wave-uniform (s_load), 64 coalesced stores/thread.
// fmaf chain identical to the previously-fused version (bit-exact).
// ---------------------------------------------------------------------------
__global__ __launch_bounds__(256) void dense1(const float2* __restrict__ lcct2,
                                              const float* __restrict__ lw1t,
                                              const float* __restrict__ lb1,
                                              float* __restrict__ h1) {
  int r = blockIdx.x * 256 + threadIdx.x;
  float2 l = lcct2[r];
#pragma unroll
  for (int f = 0; f < 64; f++) {
    float h = fmaf(l.y, lw1t[f * 2 + 1], fmaf(l.x, lw1t[f * 2], lb1[f]));
    h1[(size_t)f * ROWS + r] = fmaxf(h, 0.f);
  }
}

// ---------------------------------------------------------------------------
// Register-tiled fp32 GEMM: out[n][m] = relu(bias[n] + sum_k w[n][k]*in[k][m])
// ---------------------------------------------------------------------------
template <int MB, int NB, int KTILES>
__global__ __launch_bounds__(256, 3) void gemm_f32(
    const float* __restrict__ in_t, const float* __restrict__ wt,
    const float* __restrict__ bias, float* __restrict__ out_t,
    int M, int Kstr) {
  constexpr int KB = 16;
  __shared__ float alds[KB * MB];
  __shared__ float wlds[KB * NB];
  int t = threadIdx.x;
  int m0 = blockIdx.x * MB;
  constexpr int TM = MB / 8;
  constexpr int TMS = (MB == 128) ? 4 : 5;
  int tm = t & (TM - 1);
  int tn = t >> TMS;
  float acc[8][8];
#pragma unroll
  for (int j = 0; j < 8; j++) {
    float b = bias[tn * 8 + j];
#pragma unroll
    for (int i = 0; i < 8; i++) acc[j][i] = b;
  }
  for (int kt = 0; kt < KTILES; kt++) {
    int k0 = kt * KB;
    __syncthreads();
    constexpr int APASS = (KB * MB / 4) / 256;
#pragma unroll
    for (int pp = 0; pp < APASS; pp++) {
      int e = pp * 256 + t;
      int kk = e / (MB / 4);
      int m4 = e - kk * (MB / 4);
      float4 v = *(const float4*)(in_t + (size_t)(k0 + kk) * M + m0 + m4 * 4);
      *(float4*)(alds + kk * MB + m4 * 4) = v;
    }
    constexpr int WPASS = (KB * NB / 4) / 256;
#pragma unroll
    for (int pp = 0; pp < WPASS; pp++) {
      int e = pp * 256 + t;
      int n = e >> 2;
      int kc = e & 3;
      float4 v = *(const float4*)(wt + (size_t)n * Kstr + k0 + kc * 4);
      wlds[(kc * 4 + 0) * NB + n] = v.x;
      wlds[(kc * 4 + 1) * NB + n] = v.y;
      wlds[(kc * 4 + 2) * NB + n] = v.z;
      wlds[(kc * 4 + 3) * NB + n] = v.w;
    }
    __syncthreads();
#pragma unroll
    for (int kk = 0; kk < KB; kk++) {
      float af[8], wf[8];
      *(float4*)(af)     = *(const float4*)(alds + kk * MB + tm * 8);
      *(float4*)(af + 4) = *(const float4*)(alds + kk * MB + tm * 8 + 4);
      *(float4*)(wf)     = *(const float4*)(wlds + kk * NB + tn * 8);
      *(float4*)(wf + 4) = *(const float4*)(wlds + kk * NB + tn * 8 + 4);
#pragma unroll
      for (int j = 0; j < 8; j++)
#pragma unroll
        for (int i = 0; i < 8; i++)
          acc[j][i] = fmaf(af[i], wf[j], acc[j][i]);
    }
  }
#pragma unroll
  for (int j = 0; j < 8; j++) {
    int n = tn * 8 + j;
    float4 o0, o1;
    o0.x = fmaxf(acc[j][0], 0.f); o0.y = fmaxf(acc[j][1], 0.f);
    o0.z = fmaxf(acc[j][2], 0.f); o0.w = fmaxf(acc[j][3], 0.f);
    o1.x = fmaxf(acc[j][4], 0.f); o1.y = fmaxf(acc[j][5], 0.f);
    o1.z = fmaxf(acc[j][6], 0.f); o1.w = fmaxf(acc[j][7], 0.f);
    float* dst = out_t + (size_t)n * M + m0 + tm * 8;
    *(float4*)(dst) = o0;
    *(float4*)(dst + 4) = o1;
  }
}

// ---------------------------------------------------------------------------
// Max over K=5 rows -> lftx rows 2..65 ; rows 0..1 = x passthrough.
// ---------------------------------------------------------------------------
__global__ __launch_bounds__(256) void maxpack(const float* __restrict__ h3,
                                               const float* __restrict__ x,
                                               float* __restrict__ lftx) {
  int idx = blockIdx.x * 256 + threadIdx.x;
  int f = idx >> 15;
  int p = idx & (PTS - 1);
  if (f < 64) {
    const float* hr = h3 + (size_t)f * ROWS + (size_t)p * 5;
    float m = fmaxf(fmaxf(fmaxf(hr[0], hr[1]), fmaxf(hr[2], hr[3])), hr[4]);
    lftx[(size_t)(f + 2) * PTS + p] = m;
  } else if (f < 66) {
    int i = f - 64;
    lftx[(size_t)i * PTS + p] = x[(size_t)p * 2 + i];
  }
}

// ---------------------------------------------------------------------------
// Transpose [256][32768] feature-major head outputs into d_out row-major.
// ---------------------------------------------------------------------------
__global__ __launch_bounds__(256) void transpose_out(const float* __restrict__ o_t, float* __restrict__ out) {
  __shared__ float tile[64][65];
  int p0 = blockIdx.x * 64;
  int j0 = blockIdx.y * 64;
  int tc = threadIdx.x & 63, tr = threadIdx.x >> 6;
#pragma unroll
  for (int rr = 0; rr < 16; rr++) {
    int j = tr + rr * 4;
    tile[j][tc] = o_t[(size_t)(j0 + j) * PTS + p0 + tc];
  }
  __syncthreads();
#pragma unroll
  for (int rr = 0; rr < 16; rr++) {
    int pl = tr + rr * 4;
    int p = p0 + pl;
    int j = j0 + tc;
    float v = tile[tc][pl];
    size_t o = (j < 128) ? ((size_t)p * 128 + j)
                         : ((size_t)4194304 + (size_t)p * 128 + (j - 128));
    out[o] = v;
  }
}

// ---------------------------------------------------------------------------
extern "C" void kernel_launch(void* const* d_in, const int* in_sizes, int n_in,
                              void* d_out, int out_size, void* d_ws, size_t ws_size,
                              hipStream_t stream) {
  const float* x   = (const float*)d_in[0];
  const float* lb1 = (const float*)d_in[2];
  const float* lb2 = (const float*)d_in[4];
  const float* lb3 = (const float*)d_in[6];
  const float* cb1 = (const float*)d_in[8];
  const float* cb2 = (const float*)d_in[10];
  const float* tb1 = (const float*)d_in[12];
  const float* tb2 = (const float*)d_in[14];

  float* out = (float*)d_out;
  float* angle_out = out + 8388608;
  float* axes_out  = out + 8421376;

  // Workspace (floats), lifetime-overlapped:
  //   wt    [67712]
  //   R1    [10485760]  ipart (knn->merge, 4M u32) then h3 (l3->maxpack)
  //   R2    [10485760]  h1 (dense1->l2) then a1 (c1->c2, t1->t2)
  //   R3    [20971520]  h2 (l2->l3) then outct+outtt (heads->transpose)
  //   lftx  [2621440]
  //   lcct2 [327680]    interleaved (l0,l1) per row
  // total ~44.96M floats = 179.8 MB (ws >= 228 MB proven in R5)
  float* W = (float*)d_ws;
  float* wt    = W;
  float* R1    = W + 67712;
  float* R2    = R1 + 10485760;
  float* R3    = R2 + 10485760;
  float* lftx  = R3 + 20971520;
  float* lcct2 = lftx + 2621440;
  unsigned int* ipart = (unsigned int*)R1;
  float* h3    = R1;
  float* h1    = R2;
  float* a1    = R2;
  float* h2    = R3;
  float* outct = R3;
  float* outtt = R3 + 4194304;

  prep_w<<<7, 256, 0, stream>>>((const float*)d_in[1], (const float*)d_in[3], (const float*)d_in[5],
                                (const float*)d_in[7], (const float*)d_in[9],
                                (const float*)d_in[11], (const float*)d_in[13], wt);
  knn_scan<<<2048, 256, 0, stream>>>(x, ipart);
  merge_geom<<<256, 128, 0, stream>>>(x, ipart, (float2*)lcct2, angle_out, (float2*)axes_out);
  dense1<<<ROWS / 256, 256, 0, stream>>>((const float2*)lcct2, wt + 0, lb1, h1);

  gemm_f32<128, 128, 4><<<ROWS / 128, 256, 0, stream>>>(h1, wt + 128, lb2, h2, ROWS, 64);
  gemm_f32<256, 64, 8><<<ROWS / 256, 256, 0, stream>>>(h2, wt + 8320, lb3, h3, ROWS, 128);
  maxpack<<<(66 * PTS) / 256, 256, 0, stream>>>(h3, x, lftx);

  gemm_f32<128, 128, 5><<<PTS / 128, 256, 0, stream>>>(lftx, wt + 16512, cb1, a1, PTS, 80);
  gemm_f32<128, 128, 8><<<PTS / 128, 256, 0, stream>>>(a1, wt + 26752, cb2, outct, PTS, 128);
  gemm_f32<128, 128, 4><<<PTS / 128, 256, 0, stream>>>(lftx + 2 * PTS, wt + 43136, tb1, a1, PTS, 64);
  gemm_f32<128, 128, 8><<<PTS / 128, 256, 0, stream>>>(a1, wt + 51328, tb2, outtt, PTS, 128);

  transpose_out<<<dim3(512, 4), 256, 0, stream>>>(outct, out);
}